// Round 3
// baseline (537.978 us; speedup 1.0000x reference)
//
#include <hip/hip_runtime.h>

#define NN 50000
#define NE 800000
#define NG 512
#define FIN 128
#define HID 256
#define NBUK 196   // buckets of 256 node ids: ceil(50000/256)

typedef short short8 __attribute__((ext_vector_type(8)));
typedef float f32x4 __attribute__((ext_vector_type(4)));
typedef float f32x2 __attribute__((ext_vector_type(2)));
typedef unsigned short u16x8 __attribute__((ext_vector_type(8)));
typedef unsigned int u32x2 __attribute__((ext_vector_type(2)));

static inline int cdiv(int a, int b) { return (a + b - 1) / b; }

static __device__ inline unsigned short f2bf(float f) {
    unsigned int u = __float_as_uint(f);
    unsigned int r = (u + 0x7FFF + ((u >> 16) & 1)) >> 16;  // RNE
    return (unsigned short)r;
}
static __device__ inline float bf2f(unsigned short h) {
    return __uint_as_float(((unsigned int)h) << 16);
}
static __device__ inline float bflo(unsigned int p) { return __uint_as_float(p << 16); }
static __device__ inline float bfhi(unsigned int p) { return __uint_as_float(p & 0xFFFF0000u); }

// packed fp32 add (gfx90a+): 1 instr for 2 lane-local f32 adds
static __device__ __forceinline__ f32x2 pkadd(f32x2 a, f32x2 b) {
    f32x2 r;
    asm("v_pk_add_f32 %0, %1, %2" : "=v"(r) : "v"(a), "v"(b));
    return r;
}

typedef __attribute__((address_space(1))) unsigned int gu32;
typedef __attribute__((address_space(3))) unsigned int lu32;
static __device__ __forceinline__ void gload16(const unsigned short* g, unsigned short* l) {
    __builtin_amdgcn_global_load_lds((const gu32*)(const void*)g, (lu32*)(void*)l, 16, 0, 0);
}

// ---- CSR build, bucket-sort style (no per-edge global atomics) ----

// coarse 196-bucket histogram of dst, LDS-privatized
__global__ __launch_bounds__(256) void hist_bucket_kernel(const int* __restrict__ dst,
                                                          int* __restrict__ gbuk) {
    __shared__ int lh[NBUK];
    int tid = threadIdx.x;
    for (int j = tid; j < NBUK; j += 256) lh[j] = 0;
    __syncthreads();
    int base = blockIdx.x * 2048;
    #pragma unroll
    for (int k = 0; k < 8; ++k) {
        int i = base + k * 256 + tid;
        if (i < NE) atomicAdd(&lh[dst[i] >> 8], 1);
    }
    __syncthreads();
    for (int j = tid; j < NBUK; j += 256) if (lh[j]) atomicAdd(&gbuk[j], lh[j]);
}

// batch is sorted: goff by boundary detection, no atomics
__global__ void goff_kernel(const int* __restrict__ batch, int* __restrict__ goff) {
    int i = blockIdx.x * 256 + threadIdx.x;
    if (i >= NN) return;
    int b = batch[i];
    int pb = (i == 0) ? -1 : batch[i - 1];
    for (int g = pb + 1; g <= b; ++g) goff[g] = i;
    if (i == NN - 1) for (int g = b + 1; g <= NG; ++g) goff[g] = NN;
}

// single-block exclusive scan of gbuk[196] -> bukoff[197], plus cursor copy
__global__ void buk_scan_kernel(const int* __restrict__ gbuk, int* __restrict__ bukoff,
                                int* __restrict__ bukcur) {
    __shared__ int ws[4];
    int tid = threadIdx.x, lane = tid & 63, wid = tid >> 6;
    int v = (tid < NBUK) ? gbuk[tid] : 0;
    int incl = v;
    #pragma unroll
    for (int off = 1; off < 64; off <<= 1) {
        int u = __shfl_up(incl, off, 64);
        if (lane >= off) incl += u;
    }
    if (lane == 63) ws[wid] = incl;
    __syncthreads();
    int woff = 0;
    for (int w = 0; w < wid; ++w) woff += ws[w];
    int ex = woff + incl - v;
    if (tid < NBUK) { bukoff[tid] = ex; bukcur[tid] = ex; }
    if (tid == NBUK - 1) bukoff[NBUK] = ex + v;
}

// scatter edges into bucket-contiguous pairs[]; one global atomic per block per bucket
__global__ __launch_bounds__(256) void scatter_kernel(const int* __restrict__ src,
                                                      const int* __restrict__ dst,
                                                      int* __restrict__ bukcur,
                                                      unsigned int* __restrict__ pairs) {
    __shared__ int lh[NBUK];
    __shared__ int lbase[NBUK];
    int tid = threadIdx.x;
    for (int j = tid; j < NBUK; j += 256) lh[j] = 0;
    __syncthreads();
    int base = blockIdx.x * 2048;
    int d[8], s[8];
    #pragma unroll
    for (int k = 0; k < 8; ++k) {
        int i = base + k * 256 + tid;
        if (i < NE) {
            d[k] = dst[i]; s[k] = src[i];
            atomicAdd(&lh[d[k] >> 8], 1);
        } else d[k] = -1;
    }
    __syncthreads();
    for (int j = tid; j < NBUK; j += 256) lbase[j] = lh[j] ? atomicAdd(&bukcur[j], lh[j]) : 0;
    __syncthreads();
    for (int j = tid; j < NBUK; j += 256) lh[j] = 0;
    __syncthreads();
    #pragma unroll
    for (int k = 0; k < 8; ++k) {
        if (d[k] >= 0) {
            int b = d[k] >> 8;
            int loc = atomicAdd(&lh[b], 1);
            pairs[lbase[b] + loc] = ((unsigned int)s[k] << 16) | (unsigned int)(d[k] & 255);
        }
    }
}

// per-bucket fine CSR: row_ptr, col8 (pre-shifted src: col<<3 = uint2-unit row offset),
// dis, plus degree histogram for the counting sort (one block per bucket)
__global__ __launch_bounds__(256) void local_csr_kernel(const unsigned int* __restrict__ pairs,
                                                        const int* __restrict__ bukoff,
                                                        int* __restrict__ row_ptr,
                                                        int* __restrict__ col8,
                                                        float* __restrict__ dis,
                                                        int* __restrict__ dh) {
    __shared__ int fcnt[256];
    __shared__ int foff[256];
    __shared__ int fws[4];
    __shared__ int dhl[256];
    int b = blockIdx.x, tid = threadIdx.x;
    int beg = bukoff[b], end = bukoff[b + 1];
    fcnt[tid] = 0;
    dhl[tid] = 0;
    __syncthreads();
    for (int i = beg + tid; i < end; i += 256) atomicAdd(&fcnt[pairs[i] & 255], 1);
    __syncthreads();
    int lane = tid & 63, wid = tid >> 6;
    int v = fcnt[tid], incl = v;
    #pragma unroll
    for (int off = 1; off < 64; off <<= 1) {
        int u = __shfl_up(incl, off, 64);
        if (lane >= off) incl += u;
    }
    if (lane == 63) fws[wid] = incl;
    __syncthreads();
    int woff = 0;
    for (int w = 0; w < wid; ++w) woff += fws[w];
    int ex = woff + incl - v;  // exclusive fine offset
    foff[tid] = ex;
    int gid = b * 256 + tid;
    if (gid < NN) {
        row_ptr[gid] = beg + ex;
        dis[gid] = rsqrtf((float)v + 1.0f);
        atomicAdd(&dhl[v > 255 ? 255 : v], 1);  // degree histogram (real nodes only)
    }
    if (b == 0 && tid == 0) row_ptr[NN] = NE;
    __syncthreads();
    if (dhl[tid]) atomicAdd(&dh[tid], dhl[tid]);
    // scatter src into col8 using foff as LDS cursors
    for (int i = beg + tid; i < end; i += 256) {
        unsigned int p = pairs[i];
        int loc = atomicAdd(&foff[p & 255], 1);
        col8[beg + loc] = (int)(p >> 16) << 3;
    }
}

// exclusive scan of 256-bin degree histogram -> cursors for the counting sort
__global__ void dscan_kernel(const int* __restrict__ dh, int* __restrict__ dcur) {
    __shared__ int ws[4];
    int tid = threadIdx.x, lane = tid & 63, wid = tid >> 6;
    int v = dh[tid], incl = v;
    #pragma unroll
    for (int off = 1; off < 64; off <<= 1) {
        int u = __shfl_up(incl, off, 64);
        if (lane >= off) incl += u;
    }
    if (lane == 63) ws[wid] = incl;
    __syncthreads();
    int woff = 0;
    for (int w = 0; w < wid; ++w) woff += ws[w];
    dcur[tid] = woff + incl - v;
}

// counting-sort scatter: perm lists node ids in ascending-degree order
__global__ void dperm_kernel(const int* __restrict__ row_ptr, int* __restrict__ dcur,
                             int* __restrict__ perm) {
    int i = blockIdx.x * 256 + threadIdx.x;
    if (i >= NN) return;
    int d = row_ptr[i + 1] - row_ptr[i];
    if (d > 255) d = 255;
    perm[atomicAdd(&dcur[d], 1)] = i;
}

// Xb[s][i][f'] = bf16(dis[i] * x[i][f])  -- blocked layout, 4 slices of 32 feats
__global__ void cast_scale_kernel(const float* __restrict__ x, const float* __restrict__ dis,
                                  unsigned short* __restrict__ Xb, int n4) {
    int i = blockIdx.x * 256 + threadIdx.x;  // float4 index over [NN][128]
    if (i < n4) {
        int node = i >> 5;   // 32 float4 per row
        int f4 = i & 31;     // float4 index within row
        int s = f4 >> 3;     // slice = feat>>5
        int o = f4 & 7;      // float4 within the 32-feat slice
        float dv = dis[node];
        float4 v = ((const float4*)x)[i];
        ushort4 w;
        w.x = f2bf(dv * v.x); w.y = f2bf(dv * v.y); w.z = f2bf(dv * v.z); w.w = f2bf(dv * v.w);
        ((ushort4*)Xb)[((size_t)s * NN + (size_t)node) * 8 + o] = w;
    }
}

// all three weights transposed+cast in one dispatch: W [K,256] fp32 -> Wt [256,K] bf16
__global__ void tcast_all_kernel(const float* __restrict__ W1, const float* __restrict__ W2,
                                 const float* __restrict__ W3,
                                 unsigned short* __restrict__ W1t, unsigned short* __restrict__ W2t,
                                 unsigned short* __restrict__ W3t) {
    int idx = blockIdx.x * 256 + threadIdx.x;
    if (idx < FIN * 256) {
        int n = idx / FIN, k = idx - n * FIN;
        W1t[idx] = f2bf(W1[(size_t)k * 256 + n]);
    } else if (idx < FIN * 256 + HID * 256) {
        int t = idx - FIN * 256;
        int n = t / HID, k = t - n * HID;
        W2t[t] = f2bf(W2[(size_t)k * 256 + n]);
    } else {
        int t = idx - FIN * 256 - HID * 256;
        int n = t / HID, k = t - n * HID;
        W3t[t] = f2bf(W3[(size_t)k * 256 + n]);
    }
}

// 128x128 GEMM, BK=32, global_load_lds staging, LDS-bounce coalesced epilogue.
// A:[M,K] bf16 row-major, Bt:[256,K] bf16.
// MODE 0: Hs = bf16(dis[row]*relu(acc + bias[col])) -> BLOCKED [8][M][32] (feeds slice-agg)
// MODE 1: Hf = bf16(relu(acc + bias[col]))          -> row-major [M][256] (feeds pooling)
#define CLD 136   // C-tile LDS row stride in shorts (mult of 8 -> 16B-aligned rows)
template <int MODE>
__global__ __launch_bounds__(256) void gemm128_kernel(
        const unsigned short* __restrict__ A, const unsigned short* __restrict__ Bt,
        const float* __restrict__ dis, const float* __restrict__ bias,
        unsigned short* __restrict__ Cout, int M, int K) {
    __shared__ unsigned short smem[128 * CLD];  // K-loop: As=smem[0:4096], Bs=smem[4096:8192]
    unsigned short* As = smem;
    unsigned short* Bs = smem + 4096;
    const int tid = threadIdx.x;
    const int bm = blockIdx.x * 128, bn = blockIdx.y * 128;
    const int wave = tid >> 6, lane = tid & 63;
    const int l16 = lane & 15, quad = lane >> 4;
    const int wm = (wave & 1) * 64, wn = (wave >> 1) * 64;

    int srow0 = tid >> 2, skc = (tid & 3) * 8;
    int srow1 = (256 + tid) >> 2;
    int ar0 = bm + srow0; if (ar0 > M - 1) ar0 = M - 1;
    int ar1 = bm + srow1; if (ar1 > M - 1) ar1 = M - 1;

    f32x4 acc[4][4];
    #pragma unroll
    for (int i = 0; i < 4; ++i)
        #pragma unroll
        for (int j = 0; j < 4; ++j) acc[i][j] = (f32x4){0.f, 0.f, 0.f, 0.f};

    for (int k0 = 0; k0 < K; k0 += 32) {
        gload16(A + (size_t)ar0 * K + k0 + skc, &As[(size_t)tid * 8]);
        gload16(A + (size_t)ar1 * K + k0 + skc, &As[(size_t)(256 + tid) * 8]);
        gload16(Bt + (size_t)(bn + srow0) * K + k0 + skc, &Bs[(size_t)tid * 8]);
        gload16(Bt + (size_t)(bn + srow1) * K + k0 + skc, &Bs[(size_t)(256 + tid) * 8]);
        __syncthreads();
        short8 af[4], bf[4];
        #pragma unroll
        for (int mt = 0; mt < 4; ++mt) af[mt] = *(const short8*)&As[(wm + mt * 16 + l16) * 32 + quad * 8];
        #pragma unroll
        for (int nt = 0; nt < 4; ++nt) bf[nt] = *(const short8*)&Bs[(wn + nt * 16 + l16) * 32 + quad * 8];
        #pragma unroll
        for (int mt = 0; mt < 4; ++mt)
            #pragma unroll
            for (int nt = 0; nt < 4; ++nt)
                acc[mt][nt] = __builtin_amdgcn_mfma_f32_16x16x32_bf16(af[mt], bf[nt], acc[mt][nt], 0, 0, 0);
        __syncthreads();
    }
    // phase 1: acc -> LDS tile (bf16), bias/relu/dis applied.  C/D: col=l16+16nt+wn, row=quad*4+r+16mt+wm
    float bv[4];
    #pragma unroll
    for (int nt = 0; nt < 4; ++nt) bv[nt] = bias[bn + wn + nt * 16 + l16];
    #pragma unroll
    for (int mt = 0; mt < 4; ++mt) {
        #pragma unroll
        for (int r = 0; r < 4; ++r) {
            int lrow = wm + mt * 16 + quad * 4 + r;
            int grow = bm + lrow; if (grow > M - 1) grow = M - 1;
            float dv = (MODE == 0) ? dis[grow] : 1.0f;
            #pragma unroll
            for (int nt = 0; nt < 4; ++nt) {
                float v = fmaxf(acc[mt][nt][r] + bv[nt], 0.f);
                if (MODE == 0) v *= dv;
                smem[lrow * CLD + wn + nt * 16 + l16] = f2bf(v);
            }
        }
    }
    __syncthreads();
    // phase 2: LDS -> global, 16B coalesced chunks (2048 chunks, 8 per thread)
    for (int c = tid; c < 2048; c += 256) {
        int lrow = c >> 4, coff = (c & 15) << 3;
        int grow = bm + lrow;
        if (grow < M) {
            if (MODE == 0) {
                int gcol = bn + coff;
                int s = gcol >> 5, o = gcol & 31;  // blocked [8][M][32]
                *(u16x8*)(Cout + ((size_t)s * M + (size_t)grow) * 32 + o) =
                    *(const u16x8*)&smem[lrow * CLD + coff];
            } else {
                *(u16x8*)(Cout + (size_t)grow * HID + bn + coff) =
                    *(const u16x8*)&smem[lrow * CLD + coff];
            }
        }
    }
}
#undef CLD

// Feature-slice-blocked aggregation, v2: 8 lanes/node x 8 B (u32x2), degree-sorted.
// In: Hb blocked [S][NN][32] bf16 (slice table 3.2 MB, resident in one XCD's 4 MB L2
//     via slice = bid & (S-1) round-robin pinning -- verified by FETCH_SIZE ~27 MB).
// perm: node ids in ascending-degree order -> all 8 nodes of a wave (32 of a block)
//     have ~equal degree -> no divergence waste, uniform unrolled trip counts.
// Out row-major [NN][S*32]: Out[v] = bf16(dis[v]*(sum_N Hb[u] + Hb[v])).
template <int S>
__global__ __launch_bounds__(256) void agg_slice_kernel(
        const unsigned short* __restrict__ Hb, const int* __restrict__ row_ptr,
        const int* __restrict__ col8, const int* __restrict__ perm,
        const float* __restrict__ dis,
        unsigned short* __restrict__ Out, int n) {
    constexpr int LOGS = (S == 8) ? 3 : 2;
    int bid = blockIdx.x;
    int s = bid & (S - 1);
    int idx = (bid >> LOGS) * 32 + (threadIdx.x >> 3);
    if (idx >= n) return;
    int node = perm[idx];
    int lane8 = threadIdx.x & 7;
    const u32x2* Hv = (const u32x2*)Hb + (size_t)s * NN * 8;
    u32x2 p = Hv[node * 8 + lane8];  // self loop
    f32x2 a01 = {bflo(p.x), bfhi(p.x)};
    f32x2 a23 = {bflo(p.y), bfhi(p.y)};
    int e = row_ptr[node], end = row_ptr[node + 1];
    for (; e + 8 <= end; e += 8) {
        u32x2 m[8];
        #pragma unroll
        for (int j = 0; j < 8; ++j) m[j] = Hv[col8[e + j] + lane8];
        #pragma unroll
        for (int j = 0; j < 8; ++j) {
            f32x2 lo = {bflo(m[j].x), bfhi(m[j].x)};
            f32x2 hi = {bflo(m[j].y), bfhi(m[j].y)};
            a01 = pkadd(a01, lo);
            a23 = pkadd(a23, hi);
        }
    }
    for (; e < end; ++e) {
        u32x2 m = Hv[col8[e] + lane8];
        f32x2 lo = {bflo(m.x), bfhi(m.x)};
        f32x2 hi = {bflo(m.y), bfhi(m.y)};
        a01 = pkadd(a01, lo);
        a23 = pkadd(a23, hi);
    }
    float dv = dis[node];
    u32x2 o;
    o.x = (unsigned int)f2bf(dv * a01.x) | ((unsigned int)f2bf(dv * a01.y) << 16);
    o.y = (unsigned int)f2bf(dv * a23.x) | ((unsigned int)f2bf(dv * a23.y) << 16);
    __builtin_nontemporal_store(o, (u32x2*)Out + (size_t)node * (S * 8) + s * 8 + lane8);
}

// one block per graph: mean-pool (bf16 Hf) + concat + FC1(relu) + FC2
__global__ __launch_bounds__(256) void pool_mlp_kernel(
        const unsigned short* __restrict__ H, const int* __restrict__ goff,
        const float* __restrict__ mol, const float* __restrict__ rings,
        const float* __restrict__ fcW1, const float* __restrict__ fcb1,
        const float* __restrict__ fcW2, const float* __restrict__ fcb2,
        float* __restrict__ out) {
    __shared__ float s_hg[258];
    __shared__ float s_t[196];
    int g = blockIdx.x, tid = threadIdx.x;
    int beg = goff[g], end = goff[g + 1];
    float acc = 0.f;
    for (int i = beg; i < end; ++i) acc += bf2f(H[(size_t)i * HID + tid]);
    s_hg[tid] = acc / fmaxf((float)(end - beg), 1.0f);
    if (tid == 0) { s_hg[256] = mol[g]; s_hg[257] = rings[g]; }
    __syncthreads();
    if (tid < 196) {
        float a = fcb1[tid];
        for (int k = 0; k < 258; ++k) a = fmaf(s_hg[k], fcW1[k * 196 + tid], a);
        s_t[tid] = fmaxf(a, 0.f);
    }
    __syncthreads();
    if (tid < 16) {
        float a = fcb2[tid];
        for (int k = 0; k < 196; ++k) a = fmaf(s_t[k], fcW2[k * 16 + tid], a);
        out[g * 16 + tid] = a;
    }
}

extern "C" void kernel_launch(void* const* d_in, const int* in_sizes, int n_in,
                              void* d_out, int out_size, void* d_ws, size_t ws_size,
                              hipStream_t stream) {
    const float* x     = (const float*)d_in[0];
    const int*   ei    = (const int*)d_in[1];
    const int*   batch = (const int*)d_in[2];
    const float* mol   = (const float*)d_in[3];
    const float* rings = (const float*)d_in[4];
    const float* W1 = (const float*)d_in[5];
    const float* b1 = (const float*)d_in[6];
    const float* W2 = (const float*)d_in[7];
    const float* b2 = (const float*)d_in[8];
    const float* W3 = (const float*)d_in[9];
    const float* b3 = (const float*)d_in[10];
    const float* fcW1 = (const float*)d_in[11];
    const float* fcb1 = (const float*)d_in[12];
    const float* fcW2 = (const float*)d_in[13];
    const float* fcb2 = (const float*)d_in[14];
    float* out = (float*)d_out;
    const int* src = ei;
    const int* dst = ei + NE;

    char* w = (char*)d_ws;
    auto alloc = [&](size_t bytes) {
        char* p = w;
        w += (bytes + 255) & ~(size_t)255;
        return p;
    };
    int*   gbuk    = (int*)alloc((size_t)NBUK * 4);
    int*   bukoff  = (int*)alloc((size_t)(NBUK + 1) * 4);
    int*   bukcur  = (int*)alloc((size_t)NBUK * 4);
    int*   row_ptr = (int*)alloc((size_t)(NN + 1) * 4);
    int*   goff    = (int*)alloc((size_t)(NG + 1) * 4);
    float* dis     = (float*)alloc((size_t)NN * 4);
    int*   dh      = (int*)alloc((size_t)256 * 4);
    int*   dcur    = (int*)alloc((size_t)256 * 4);
    int*   perm    = (int*)alloc((size_t)NN * 4);
    unsigned int* pairs = (unsigned int*)alloc((size_t)NE * 4);
    int*   col8    = (int*)alloc((size_t)NE * 4);
    unsigned short* Xs  = (unsigned short*)alloc((size_t)NN * FIN * 2);  // blocked [4][NN][32]
    unsigned short* Xa  = (unsigned short*)alloc((size_t)NN * FIN * 2);  // row-major
    unsigned short* Hs  = (unsigned short*)alloc((size_t)NN * HID * 2);  // blocked [8][NN][32]
    unsigned short* Ga  = (unsigned short*)alloc((size_t)NN * HID * 2);  // row-major
    unsigned short* Hf  = (unsigned short*)alloc((size_t)NN * HID * 2);  // row-major
    unsigned short* W1t = (unsigned short*)alloc((size_t)FIN * HID * 2);
    unsigned short* W2t = (unsigned short*)alloc((size_t)HID * HID * 2);
    unsigned short* W3t = (unsigned short*)alloc((size_t)HID * HID * 2);

    hipMemsetAsync(gbuk, 0, (size_t)NBUK * 4, stream);
    hipMemsetAsync(dh, 0, (size_t)256 * 4, stream);
    int eb = cdiv(NE, 2048);  // 391
    hist_bucket_kernel<<<eb, 256, 0, stream>>>(dst, gbuk);
    goff_kernel<<<cdiv(NN, 256), 256, 0, stream>>>(batch, goff);
    buk_scan_kernel<<<1, 256, 0, stream>>>(gbuk, bukoff, bukcur);
    scatter_kernel<<<eb, 256, 0, stream>>>(src, dst, bukcur, pairs);
    local_csr_kernel<<<NBUK, 256, 0, stream>>>(pairs, bukoff, row_ptr, col8, dis, dh);
    dscan_kernel<<<1, 256, 0, stream>>>(dh, dcur);
    dperm_kernel<<<cdiv(NN, 256), 256, 0, stream>>>(row_ptr, dcur, perm);

    cast_scale_kernel<<<cdiv(NN * FIN / 4, 256), 256, 0, stream>>>(x, dis, Xs, NN * FIN / 4);
    tcast_all_kernel<<<cdiv((FIN + HID + HID) * 256, 256), 256, 0, stream>>>(W1, W2, W3, W1t, W2t, W3t);

    dim3 ggrid(cdiv(NN, 128), 2);
    int achunks = cdiv(NN, 32);  // 1563
    // all layers: aggregate-then-transform (aggregation commutes with @W)
    agg_slice_kernel<4><<<4 * achunks, 256, 0, stream>>>(Xs, row_ptr, col8, perm, dis, Xa, NN);
    gemm128_kernel<0><<<ggrid, 256, 0, stream>>>(Xa, W1t, dis, b1, Hs, NN, FIN);  // Hs1 blocked
    agg_slice_kernel<8><<<8 * achunks, 256, 0, stream>>>(Hs, row_ptr, col8, perm, dis, Ga, NN);
    gemm128_kernel<0><<<ggrid, 256, 0, stream>>>(Ga, W2t, dis, b2, Hs, NN, HID);  // Hs2 blocked
    agg_slice_kernel<8><<<8 * achunks, 256, 0, stream>>>(Hs, row_ptr, col8, perm, dis, Ga, NN);
    gemm128_kernel<1><<<ggrid, 256, 0, stream>>>(Ga, W3t, dis, b3, Hf, NN, HID);  // Hf row-major
    pool_mlp_kernel<<<NG, 256, 0, stream>>>(Hf, goff, mol, rings, fcW1, fcb1, fcW2, fcb2, out);
}

// Round 4
// 410.374 us; speedup vs baseline: 1.3109x; 1.3109x over previous
//
#include <hip/hip_runtime.h>

#define NN 50000
#define NE 800000
#define NG 512
#define FIN 128
#define HID 256
#define NBUK 196   // buckets of 256 node ids: ceil(50000/256)

typedef short short8 __attribute__((ext_vector_type(8)));
typedef float f32x4 __attribute__((ext_vector_type(4)));
typedef float f32x2 __attribute__((ext_vector_type(2)));
typedef unsigned short u16x8 __attribute__((ext_vector_type(8)));
typedef unsigned int u32x2 __attribute__((ext_vector_type(2)));

static inline int cdiv(int a, int b) { return (a + b - 1) / b; }

static __device__ inline unsigned short f2bf(float f) {
    unsigned int u = __float_as_uint(f);
    unsigned int r = (u + 0x7FFF + ((u >> 16) & 1)) >> 16;  // RNE
    return (unsigned short)r;
}
static __device__ inline float bf2f(unsigned short h) {
    return __uint_as_float(((unsigned int)h) << 16);
}
static __device__ inline float bflo(unsigned int p) { return __uint_as_float(p << 16); }
static __device__ inline float bfhi(unsigned int p) { return __uint_as_float(p & 0xFFFF0000u); }

// packed fp32 add (gfx90a+): 1 instr for 2 lane-local f32 adds
static __device__ __forceinline__ f32x2 pkadd(f32x2 a, f32x2 b) {
    f32x2 r;
    asm("v_pk_add_f32 %0, %1, %2" : "=v"(r) : "v"(a), "v"(b));
    return r;
}

typedef __attribute__((address_space(1))) unsigned int gu32;
typedef __attribute__((address_space(3))) unsigned int lu32;
static __device__ __forceinline__ void gload16(const unsigned short* g, unsigned short* l) {
    __builtin_amdgcn_global_load_lds((const gu32*)(const void*)g, (lu32*)(void*)l, 16, 0, 0);
}

// ---- CSR build, bucket-sort style (no per-edge global atomics) ----

// coarse 196-bucket histogram of dst, LDS-privatized
__global__ __launch_bounds__(256) void hist_bucket_kernel(const int* __restrict__ dst,
                                                          int* __restrict__ gbuk) {
    __shared__ int lh[NBUK];
    int tid = threadIdx.x;
    for (int j = tid; j < NBUK; j += 256) lh[j] = 0;
    __syncthreads();
    int base = blockIdx.x * 2048;
    #pragma unroll
    for (int k = 0; k < 8; ++k) {
        int i = base + k * 256 + tid;
        if (i < NE) atomicAdd(&lh[dst[i] >> 8], 1);
    }
    __syncthreads();
    for (int j = tid; j < NBUK; j += 256) if (lh[j]) atomicAdd(&gbuk[j], lh[j]);
}

// batch is sorted: goff by boundary detection, no atomics
__global__ void goff_kernel(const int* __restrict__ batch, int* __restrict__ goff) {
    int i = blockIdx.x * 256 + threadIdx.x;
    if (i >= NN) return;
    int b = batch[i];
    int pb = (i == 0) ? -1 : batch[i - 1];
    for (int g = pb + 1; g <= b; ++g) goff[g] = i;
    if (i == NN - 1) for (int g = b + 1; g <= NG; ++g) goff[g] = NN;
}

// single-block exclusive scan of gbuk[196] -> bukoff[197], plus cursor copy
__global__ void buk_scan_kernel(const int* __restrict__ gbuk, int* __restrict__ bukoff,
                                int* __restrict__ bukcur) {
    __shared__ int ws[4];
    int tid = threadIdx.x, lane = tid & 63, wid = tid >> 6;
    int v = (tid < NBUK) ? gbuk[tid] : 0;
    int incl = v;
    #pragma unroll
    for (int off = 1; off < 64; off <<= 1) {
        int u = __shfl_up(incl, off, 64);
        if (lane >= off) incl += u;
    }
    if (lane == 63) ws[wid] = incl;
    __syncthreads();
    int woff = 0;
    for (int w = 0; w < wid; ++w) woff += ws[w];
    int ex = woff + incl - v;
    if (tid < NBUK) { bukoff[tid] = ex; bukcur[tid] = ex; }
    if (tid == NBUK - 1) bukoff[NBUK] = ex + v;
}

// scatter edges into bucket-contiguous pairs[]; one global atomic per block per bucket
__global__ __launch_bounds__(256) void scatter_kernel(const int* __restrict__ src,
                                                      const int* __restrict__ dst,
                                                      int* __restrict__ bukcur,
                                                      unsigned int* __restrict__ pairs) {
    __shared__ int lh[NBUK];
    __shared__ int lbase[NBUK];
    int tid = threadIdx.x;
    for (int j = tid; j < NBUK; j += 256) lh[j] = 0;
    __syncthreads();
    int base = blockIdx.x * 2048;
    int d[8], s[8];
    #pragma unroll
    for (int k = 0; k < 8; ++k) {
        int i = base + k * 256 + tid;
        if (i < NE) {
            d[k] = dst[i]; s[k] = src[i];
            atomicAdd(&lh[d[k] >> 8], 1);
        } else d[k] = -1;
    }
    __syncthreads();
    for (int j = tid; j < NBUK; j += 256) lbase[j] = lh[j] ? atomicAdd(&bukcur[j], lh[j]) : 0;
    __syncthreads();
    for (int j = tid; j < NBUK; j += 256) lh[j] = 0;
    __syncthreads();
    #pragma unroll
    for (int k = 0; k < 8; ++k) {
        if (d[k] >= 0) {
            int b = d[k] >> 8;
            int loc = atomicAdd(&lh[b], 1);
            pairs[lbase[b] + loc] = ((unsigned int)s[k] << 16) | (unsigned int)(d[k] & 255);
        }
    }
}

// per-bucket fine CSR: row_ptr, col8 (pre-shifted src: col<<3 = uint2-unit row offset),
// dis (one block per bucket)
__global__ __launch_bounds__(256) void local_csr_kernel(const unsigned int* __restrict__ pairs,
                                                        const int* __restrict__ bukoff,
                                                        int* __restrict__ row_ptr,
                                                        int* __restrict__ col8,
                                                        float* __restrict__ dis) {
    __shared__ int fcnt[256];
    __shared__ int foff[256];
    __shared__ int fws[4];
    int b = blockIdx.x, tid = threadIdx.x;
    int beg = bukoff[b], end = bukoff[b + 1];
    fcnt[tid] = 0;
    __syncthreads();
    for (int i = beg + tid; i < end; i += 256) atomicAdd(&fcnt[pairs[i] & 255], 1);
    __syncthreads();
    int lane = tid & 63, wid = tid >> 6;
    int v = fcnt[tid], incl = v;
    #pragma unroll
    for (int off = 1; off < 64; off <<= 1) {
        int u = __shfl_up(incl, off, 64);
        if (lane >= off) incl += u;
    }
    if (lane == 63) fws[wid] = incl;
    __syncthreads();
    int woff = 0;
    for (int w = 0; w < wid; ++w) woff += fws[w];
    int ex = woff + incl - v;  // exclusive fine offset
    foff[tid] = ex;
    int gid = b * 256 + tid;
    if (gid < NN) {
        row_ptr[gid] = beg + ex;
        dis[gid] = rsqrtf((float)v + 1.0f);
    }
    if (b == 0 && tid == 0) row_ptr[NN] = NE;
    __syncthreads();
    // scatter src into col8 using foff as LDS cursors
    for (int i = beg + tid; i < end; i += 256) {
        unsigned int p = pairs[i];
        int loc = atomicAdd(&foff[p & 255], 1);
        col8[beg + loc] = (int)(p >> 16) << 3;
    }
}

// degree histogram over all nodes, LDS-privatized (for the counting sort)
__global__ __launch_bounds__(256) void dhist_kernel(const int* __restrict__ row_ptr,
                                                    int* __restrict__ dh) {
    __shared__ int lh[256];
    int tid = threadIdx.x;
    lh[tid] = 0;
    __syncthreads();
    int i = blockIdx.x * 256 + tid;
    if (i < NN) {
        int d = row_ptr[i + 1] - row_ptr[i];
        if (d > 255) d = 255;
        atomicAdd(&lh[d], 1);
    }
    __syncthreads();
    if (lh[tid]) atomicAdd(&dh[tid], lh[tid]);
}

// exclusive scan of 256-bin degree histogram -> cursors for the counting sort
__global__ void dscan_kernel(const int* __restrict__ dh, int* __restrict__ dcur) {
    __shared__ int ws[4];
    int tid = threadIdx.x, lane = tid & 63, wid = tid >> 6;
    int v = dh[tid], incl = v;
    #pragma unroll
    for (int off = 1; off < 64; off <<= 1) {
        int u = __shfl_up(incl, off, 64);
        if (lane >= off) incl += u;
    }
    if (lane == 63) ws[wid] = incl;
    __syncthreads();
    int woff = 0;
    for (int w = 0; w < wid; ++w) woff += ws[w];
    dcur[tid] = woff + incl - v;
}

// counting-sort scatter, BLOCK-PRIVATIZED: LDS histogram + one global atomic per
// (block,bin) + LDS-rank. Replaces 50k contended global atomics (133 us!) with ~9k
// aggregated ones (hist_bucket pattern). Bin-internal order is arbitrary -- irrelevant,
// perm only groups equal-degree nodes for wave-uniform trip counts.
__global__ __launch_bounds__(256) void dperm_kernel(const int* __restrict__ row_ptr,
                                                    int* __restrict__ dcur,
                                                    int* __restrict__ perm) {
    __shared__ int lh[256];
    __shared__ int lbase[256];
    int tid = threadIdx.x;
    int i = blockIdx.x * 256 + tid;
    lh[tid] = 0;
    __syncthreads();
    int d = 0, rank = 0;
    bool ok = (i < NN);
    if (ok) {
        d = row_ptr[i + 1] - row_ptr[i];
        if (d > 255) d = 255;
        rank = atomicAdd(&lh[d], 1);  // LDS atomic: rank within this block's bin
    }
    __syncthreads();
    lbase[tid] = lh[tid] ? atomicAdd(&dcur[tid], lh[tid]) : 0;  // one global atomic per bin
    __syncthreads();
    if (ok) perm[lbase[d] + rank] = i;
}

// Xb[s][i][f'] = bf16(dis[i] * x[i][f])  -- blocked layout, 4 slices of 32 feats
__global__ void cast_scale_kernel(const float* __restrict__ x, const float* __restrict__ dis,
                                  unsigned short* __restrict__ Xb, int n4) {
    int i = blockIdx.x * 256 + threadIdx.x;  // float4 index over [NN][128]
    if (i < n4) {
        int node = i >> 5;   // 32 float4 per row
        int f4 = i & 31;     // float4 index within row
        int s = f4 >> 3;     // slice = feat>>5
        int o = f4 & 7;      // float4 within the 32-feat slice
        float dv = dis[node];
        float4 v = ((const float4*)x)[i];
        ushort4 w;
        w.x = f2bf(dv * v.x); w.y = f2bf(dv * v.y); w.z = f2bf(dv * v.z); w.w = f2bf(dv * v.w);
        ((ushort4*)Xb)[((size_t)s * NN + (size_t)node) * 8 + o] = w;
    }
}

// all three weights transposed+cast in one dispatch: W [K,256] fp32 -> Wt [256,K] bf16
__global__ void tcast_all_kernel(const float* __restrict__ W1, const float* __restrict__ W2,
                                 const float* __restrict__ W3,
                                 unsigned short* __restrict__ W1t, unsigned short* __restrict__ W2t,
                                 unsigned short* __restrict__ W3t) {
    int idx = blockIdx.x * 256 + threadIdx.x;
    if (idx < FIN * 256) {
        int n = idx / FIN, k = idx - n * FIN;
        W1t[idx] = f2bf(W1[(size_t)k * 256 + n]);
    } else if (idx < FIN * 256 + HID * 256) {
        int t = idx - FIN * 256;
        int n = t / HID, k = t - n * HID;
        W2t[t] = f2bf(W2[(size_t)k * 256 + n]);
    } else {
        int t = idx - FIN * 256 - HID * 256;
        int n = t / HID, k = t - n * HID;
        W3t[t] = f2bf(W3[(size_t)k * 256 + n]);
    }
}

// 128x128 GEMM, BK=32, global_load_lds staging, LDS-bounce coalesced epilogue.
// A:[M,K] bf16 row-major, Bt:[256,K] bf16.
// MODE 0: Hs = bf16(dis[row]*relu(acc + bias[col])) -> BLOCKED [8][M][32] (feeds slice-agg)
// MODE 1: Hf = bf16(relu(acc + bias[col]))          -> row-major [M][256] (feeds pooling)
#define CLD 136   // C-tile LDS row stride in shorts (mult of 8 -> 16B-aligned rows)
template <int MODE>
__global__ __launch_bounds__(256) void gemm128_kernel(
        const unsigned short* __restrict__ A, const unsigned short* __restrict__ Bt,
        const float* __restrict__ dis, const float* __restrict__ bias,
        unsigned short* __restrict__ Cout, int M, int K) {
    __shared__ unsigned short smem[128 * CLD];  // K-loop: As=smem[0:4096], Bs=smem[4096:8192]
    unsigned short* As = smem;
    unsigned short* Bs = smem + 4096;
    const int tid = threadIdx.x;
    const int bm = blockIdx.x * 128, bn = blockIdx.y * 128;
    const int wave = tid >> 6, lane = tid & 63;
    const int l16 = lane & 15, quad = lane >> 4;
    const int wm = (wave & 1) * 64, wn = (wave >> 1) * 64;

    int srow0 = tid >> 2, skc = (tid & 3) * 8;
    int srow1 = (256 + tid) >> 2;
    int ar0 = bm + srow0; if (ar0 > M - 1) ar0 = M - 1;
    int ar1 = bm + srow1; if (ar1 > M - 1) ar1 = M - 1;

    f32x4 acc[4][4];
    #pragma unroll
    for (int i = 0; i < 4; ++i)
        #pragma unroll
        for (int j = 0; j < 4; ++j) acc[i][j] = (f32x4){0.f, 0.f, 0.f, 0.f};

    for (int k0 = 0; k0 < K; k0 += 32) {
        gload16(A + (size_t)ar0 * K + k0 + skc, &As[(size_t)tid * 8]);
        gload16(A + (size_t)ar1 * K + k0 + skc, &As[(size_t)(256 + tid) * 8]);
        gload16(Bt + (size_t)(bn + srow0) * K + k0 + skc, &Bs[(size_t)tid * 8]);
        gload16(Bt + (size_t)(bn + srow1) * K + k0 + skc, &Bs[(size_t)(256 + tid) * 8]);
        __syncthreads();
        short8 af[4], bf[4];
        #pragma unroll
        for (int mt = 0; mt < 4; ++mt) af[mt] = *(const short8*)&As[(wm + mt * 16 + l16) * 32 + quad * 8];
        #pragma unroll
        for (int nt = 0; nt < 4; ++nt) bf[nt] = *(const short8*)&Bs[(wn + nt * 16 + l16) * 32 + quad * 8];
        #pragma unroll
        for (int mt = 0; mt < 4; ++mt)
            #pragma unroll
            for (int nt = 0; nt < 4; ++nt)
                acc[mt][nt] = __builtin_amdgcn_mfma_f32_16x16x32_bf16(af[mt], bf[nt], acc[mt][nt], 0, 0, 0);
        __syncthreads();
    }
    // phase 1: acc -> LDS tile (bf16), bias/relu/dis applied.  C/D: col=l16+16nt+wn, row=quad*4+r+16mt+wm
    float bv[4];
    #pragma unroll
    for (int nt = 0; nt < 4; ++nt) bv[nt] = bias[bn + wn + nt * 16 + l16];
    #pragma unroll
    for (int mt = 0; mt < 4; ++mt) {
        #pragma unroll
        for (int r = 0; r < 4; ++r) {
            int lrow = wm + mt * 16 + quad * 4 + r;
            int grow = bm + lrow; if (grow > M - 1) grow = M - 1;
            float dv = (MODE == 0) ? dis[grow] : 1.0f;
            #pragma unroll
            for (int nt = 0; nt < 4; ++nt) {
                float v = fmaxf(acc[mt][nt][r] + bv[nt], 0.f);
                if (MODE == 0) v *= dv;
                smem[lrow * CLD + wn + nt * 16 + l16] = f2bf(v);
            }
        }
    }
    __syncthreads();
    // phase 2: LDS -> global, 16B coalesced chunks (2048 chunks, 8 per thread)
    for (int c = tid; c < 2048; c += 256) {
        int lrow = c >> 4, coff = (c & 15) << 3;
        int grow = bm + lrow;
        if (grow < M) {
            if (MODE == 0) {
                int gcol = bn + coff;
                int s = gcol >> 5, o = gcol & 31;  // blocked [8][M][32]
                *(u16x8*)(Cout + ((size_t)s * M + (size_t)grow) * 32 + o) =
                    *(const u16x8*)&smem[lrow * CLD + coff];
            } else {
                *(u16x8*)(Cout + (size_t)grow * HID + bn + coff) =
                    *(const u16x8*)&smem[lrow * CLD + coff];
            }
        }
    }
}
#undef CLD

// Feature-slice-blocked aggregation, v2: 8 lanes/node x 8 B (u32x2), degree-sorted.
// In: Hb blocked [S][NN][32] bf16 (slice table 3.2 MB, resident in one XCD's 4 MB L2
//     via slice = bid & (S-1) round-robin pinning -- verified by FETCH_SIZE ~27 MB).
// perm: node ids grouped by degree -> all 8 nodes of a wave (32 of a block)
//     have ~equal degree -> no divergence waste, uniform unrolled trip counts.
// Out row-major [NN][S*32]: Out[v] = bf16(dis[v]*(sum_N Hb[u] + Hb[v])).
template <int S>
__global__ __launch_bounds__(256) void agg_slice_kernel(
        const unsigned short* __restrict__ Hb, const int* __restrict__ row_ptr,
        const int* __restrict__ col8, const int* __restrict__ perm,
        const float* __restrict__ dis,
        unsigned short* __restrict__ Out, int n) {
    constexpr int LOGS = (S == 8) ? 3 : 2;
    int bid = blockIdx.x;
    int s = bid & (S - 1);
    int idx = (bid >> LOGS) * 32 + (threadIdx.x >> 3);
    if (idx >= n) return;
    int node = perm[idx];
    int lane8 = threadIdx.x & 7;
    const u32x2* Hv = (const u32x2*)Hb + (size_t)s * NN * 8;
    u32x2 p = Hv[node * 8 + lane8];  // self loop
    f32x2 a01 = {bflo(p.x), bfhi(p.x)};
    f32x2 a23 = {bflo(p.y), bfhi(p.y)};
    int e = row_ptr[node], end = row_ptr[node + 1];
    for (; e + 8 <= end; e += 8) {
        u32x2 m[8];
        #pragma unroll
        for (int j = 0; j < 8; ++j) m[j] = Hv[col8[e + j] + lane8];
        #pragma unroll
        for (int j = 0; j < 8; ++j) {
            f32x2 lo = {bflo(m[j].x), bfhi(m[j].x)};
            f32x2 hi = {bflo(m[j].y), bfhi(m[j].y)};
            a01 = pkadd(a01, lo);
            a23 = pkadd(a23, hi);
        }
    }
    for (; e < end; ++e) {
        u32x2 m = Hv[col8[e] + lane8];
        f32x2 lo = {bflo(m.x), bfhi(m.x)};
        f32x2 hi = {bflo(m.y), bfhi(m.y)};
        a01 = pkadd(a01, lo);
        a23 = pkadd(a23, hi);
    }
    float dv = dis[node];
    u32x2 o;
    o.x = (unsigned int)f2bf(dv * a01.x) | ((unsigned int)f2bf(dv * a01.y) << 16);
    o.y = (unsigned int)f2bf(dv * a23.x) | ((unsigned int)f2bf(dv * a23.y) << 16);
    __builtin_nontemporal_store(o, (u32x2*)Out + (size_t)node * (S * 8) + s * 8 + lane8);
}

// one block per graph: mean-pool (bf16 Hf) + concat + FC1(relu) + FC2
__global__ __launch_bounds__(256) void pool_mlp_kernel(
        const unsigned short* __restrict__ H, const int* __restrict__ goff,
        const float* __restrict__ mol, const float* __restrict__ rings,
        const float* __restrict__ fcW1, const float* __restrict__ fcb1,
        const float* __restrict__ fcW2, const float* __restrict__ fcb2,
        float* __restrict__ out) {
    __shared__ float s_hg[258];
    __shared__ float s_t[196];
    int g = blockIdx.x, tid = threadIdx.x;
    int beg = goff[g], end = goff[g + 1];
    float acc = 0.f;
    for (int i = beg; i < end; ++i) acc += bf2f(H[(size_t)i * HID + tid]);
    s_hg[tid] = acc / fmaxf((float)(end - beg), 1.0f);
    if (tid == 0) { s_hg[256] = mol[g]; s_hg[257] = rings[g]; }
    __syncthreads();
    if (tid < 196) {
        float a = fcb1[tid];
        for (int k = 0; k < 258; ++k) a = fmaf(s_hg[k], fcW1[k * 196 + tid], a);
        s_t[tid] = fmaxf(a, 0.f);
    }
    __syncthreads();
    if (tid < 16) {
        float a = fcb2[tid];
        for (int k = 0; k < 196; ++k) a = fmaf(s_t[k], fcW2[k * 16 + tid], a);
        out[g * 16 + tid] = a;
    }
}

extern "C" void kernel_launch(void* const* d_in, const int* in_sizes, int n_in,
                              void* d_out, int out_size, void* d_ws, size_t ws_size,
                              hipStream_t stream) {
    const float* x     = (const float*)d_in[0];
    const int*   ei    = (const int*)d_in[1];
    const int*   batch = (const int*)d_in[2];
    const float* mol   = (const float*)d_in[3];
    const float* rings = (const float*)d_in[4];
    const float* W1 = (const float*)d_in[5];
    const float* b1 = (const float*)d_in[6];
    const float* W2 = (const float*)d_in[7];
    const float* b2 = (const float*)d_in[8];
    const float* W3 = (const float*)d_in[9];
    const float* b3 = (const float*)d_in[10];
    const float* fcW1 = (const float*)d_in[11];
    const float* fcb1 = (const float*)d_in[12];
    const float* fcW2 = (const float*)d_in[13];
    const float* fcb2 = (const float*)d_in[14];
    float* out = (float*)d_out;
    const int* src = ei;
    const int* dst = ei + NE;

    char* w = (char*)d_ws;
    auto alloc = [&](size_t bytes) {
        char* p = w;
        w += (bytes + 255) & ~(size_t)255;
        return p;
    };
    int*   gbuk    = (int*)alloc((size_t)NBUK * 4);
    int*   bukoff  = (int*)alloc((size_t)(NBUK + 1) * 4);
    int*   bukcur  = (int*)alloc((size_t)NBUK * 4);
    int*   row_ptr = (int*)alloc((size_t)(NN + 1) * 4);
    int*   goff    = (int*)alloc((size_t)(NG + 1) * 4);
    float* dis     = (float*)alloc((size_t)NN * 4);
    int*   dh      = (int*)alloc((size_t)256 * 4);
    int*   dcur    = (int*)alloc((size_t)256 * 4);
    int*   perm    = (int*)alloc((size_t)NN * 4);
    unsigned int* pairs = (unsigned int*)alloc((size_t)NE * 4);
    int*   col8    = (int*)alloc((size_t)NE * 4);
    unsigned short* Xs  = (unsigned short*)alloc((size_t)NN * FIN * 2);  // blocked [4][NN][32]
    unsigned short* Xa  = (unsigned short*)alloc((size_t)NN * FIN * 2);  // row-major
    unsigned short* Hs  = (unsigned short*)alloc((size_t)NN * HID * 2);  // blocked [8][NN][32]
    unsigned short* Ga  = (unsigned short*)alloc((size_t)NN * HID * 2);  // row-major
    unsigned short* Hf  = (unsigned short*)alloc((size_t)NN * HID * 2);  // row-major
    unsigned short* W1t = (unsigned short*)alloc((size_t)FIN * HID * 2);
    unsigned short* W2t = (unsigned short*)alloc((size_t)HID * HID * 2);
    unsigned short* W3t = (unsigned short*)alloc((size_t)HID * HID * 2);

    hipMemsetAsync(gbuk, 0, (size_t)NBUK * 4, stream);
    hipMemsetAsync(dh, 0, (size_t)256 * 4, stream);
    int eb = cdiv(NE, 2048);  // 391
    hist_bucket_kernel<<<eb, 256, 0, stream>>>(dst, gbuk);
    goff_kernel<<<cdiv(NN, 256), 256, 0, stream>>>(batch, goff);
    buk_scan_kernel<<<1, 256, 0, stream>>>(gbuk, bukoff, bukcur);
    scatter_kernel<<<eb, 256, 0, stream>>>(src, dst, bukcur, pairs);
    local_csr_kernel<<<NBUK, 256, 0, stream>>>(pairs, bukoff, row_ptr, col8, dis);
    dhist_kernel<<<cdiv(NN, 256), 256, 0, stream>>>(row_ptr, dh);
    dscan_kernel<<<1, 256, 0, stream>>>(dh, dcur);
    dperm_kernel<<<cdiv(NN, 256), 256, 0, stream>>>(row_ptr, dcur, perm);

    cast_scale_kernel<<<cdiv(NN * FIN / 4, 256), 256, 0, stream>>>(x, dis, Xs, NN * FIN / 4);
    tcast_all_kernel<<<cdiv((FIN + HID + HID) * 256, 256), 256, 0, stream>>>(W1, W2, W3, W1t, W2t, W3t);

    dim3 ggrid(cdiv(NN, 128), 2);
    int achunks = cdiv(NN, 32);  // 1563
    // all layers: aggregate-then-transform (aggregation commutes with @W)
    agg_slice_kernel<4><<<4 * achunks, 256, 0, stream>>>(Xs, row_ptr, col8, perm, dis, Xa, NN);
    gemm128_kernel<0><<<ggrid, 256, 0, stream>>>(Xa, W1t, dis, b1, Hs, NN, FIN);  // Hs1 blocked
    agg_slice_kernel<8><<<8 * achunks, 256, 0, stream>>>(Hs, row_ptr, col8, perm, dis, Ga, NN);
    gemm128_kernel<0><<<ggrid, 256, 0, stream>>>(Ga, W2t, dis, b2, Hs, NN, HID);  // Hs2 blocked
    agg_slice_kernel<8><<<8 * achunks, 256, 0, stream>>>(Hs, row_ptr, col8, perm, dis, Ga, NN);
    gemm128_kernel<1><<<ggrid, 256, 0, stream>>>(Ga, W3t, dis, b3, Hf, NN, HID);  // Hf row-major
    pool_mlp_kernel<<<NG, 256, 0, stream>>>(Hf, goff, mol, rings, fcW1, fcb1, fcW2, fcb2, out);
}

// Round 5
// 389.351 us; speedup vs baseline: 1.3817x; 1.0540x over previous
//
#include <hip/hip_runtime.h>

#define NN 50000
#define NE 800000
#define NG 512
#define FIN 128
#define HID 256
#define NBUK 196   // buckets of 256 node ids: ceil(50000/256)
#define SEGSZ 2048 // segment size for the locality-preserving degree sort

typedef short short8 __attribute__((ext_vector_type(8)));
typedef float f32x4 __attribute__((ext_vector_type(4)));
typedef float f32x2 __attribute__((ext_vector_type(2)));
typedef unsigned short u16x8 __attribute__((ext_vector_type(8)));
typedef unsigned int u32x2 __attribute__((ext_vector_type(2)));

static inline int cdiv(int a, int b) { return (a + b - 1) / b; }

static __device__ inline unsigned short f2bf(float f) {
    unsigned int u = __float_as_uint(f);
    unsigned int r = (u + 0x7FFF + ((u >> 16) & 1)) >> 16;  // RNE
    return (unsigned short)r;
}
static __device__ inline float bf2f(unsigned short h) {
    return __uint_as_float(((unsigned int)h) << 16);
}
static __device__ inline float bflo(unsigned int p) { return __uint_as_float(p << 16); }
static __device__ inline float bfhi(unsigned int p) { return __uint_as_float(p & 0xFFFF0000u); }

// packed fp32 add (gfx90a+): 1 instr for 2 lane-local f32 adds
static __device__ __forceinline__ f32x2 pkadd(f32x2 a, f32x2 b) {
    f32x2 r;
    asm("v_pk_add_f32 %0, %1, %2" : "=v"(r) : "v"(a), "v"(b));
    return r;
}

typedef __attribute__((address_space(1))) unsigned int gu32;
typedef __attribute__((address_space(3))) unsigned int lu32;
static __device__ __forceinline__ void gload16(const unsigned short* g, unsigned short* l) {
    __builtin_amdgcn_global_load_lds((const gu32*)(const void*)g, (lu32*)(void*)l, 16, 0, 0);
}

// ---- CSR build, bucket-sort style (no per-edge global atomics) ----

// coarse 196-bucket histogram of dst, LDS-privatized
__global__ __launch_bounds__(256) void hist_bucket_kernel(const int* __restrict__ dst,
                                                          int* __restrict__ gbuk) {
    __shared__ int lh[NBUK];
    int tid = threadIdx.x;
    for (int j = tid; j < NBUK; j += 256) lh[j] = 0;
    __syncthreads();
    int base = blockIdx.x * 2048;
    #pragma unroll
    for (int k = 0; k < 8; ++k) {
        int i = base + k * 256 + tid;
        if (i < NE) atomicAdd(&lh[dst[i] >> 8], 1);
    }
    __syncthreads();
    for (int j = tid; j < NBUK; j += 256) if (lh[j]) atomicAdd(&gbuk[j], lh[j]);
}

// batch is sorted: goff by boundary detection, no atomics
__global__ void goff_kernel(const int* __restrict__ batch, int* __restrict__ goff) {
    int i = blockIdx.x * 256 + threadIdx.x;
    if (i >= NN) return;
    int b = batch[i];
    int pb = (i == 0) ? -1 : batch[i - 1];
    for (int g = pb + 1; g <= b; ++g) goff[g] = i;
    if (i == NN - 1) for (int g = b + 1; g <= NG; ++g) goff[g] = NN;
}

// single-block exclusive scan of gbuk[196] -> bukoff[197], plus cursor copy
__global__ void buk_scan_kernel(const int* __restrict__ gbuk, int* __restrict__ bukoff,
                                int* __restrict__ bukcur) {
    __shared__ int ws[4];
    int tid = threadIdx.x, lane = tid & 63, wid = tid >> 6;
    int v = (tid < NBUK) ? gbuk[tid] : 0;
    int incl = v;
    #pragma unroll
    for (int off = 1; off < 64; off <<= 1) {
        int u = __shfl_up(incl, off, 64);
        if (lane >= off) incl += u;
    }
    if (lane == 63) ws[wid] = incl;
    __syncthreads();
    int woff = 0;
    for (int w = 0; w < wid; ++w) woff += ws[w];
    int ex = woff + incl - v;
    if (tid < NBUK) { bukoff[tid] = ex; bukcur[tid] = ex; }
    if (tid == NBUK - 1) bukoff[NBUK] = ex + v;
}

// scatter edges into bucket-contiguous pairs[]; one global atomic per block per bucket
__global__ __launch_bounds__(256) void scatter_kernel(const int* __restrict__ src,
                                                      const int* __restrict__ dst,
                                                      int* __restrict__ bukcur,
                                                      unsigned int* __restrict__ pairs) {
    __shared__ int lh[NBUK];
    __shared__ int lbase[NBUK];
    int tid = threadIdx.x;
    for (int j = tid; j < NBUK; j += 256) lh[j] = 0;
    __syncthreads();
    int base = blockIdx.x * 2048;
    int d[8], s[8];
    #pragma unroll
    for (int k = 0; k < 8; ++k) {
        int i = base + k * 256 + tid;
        if (i < NE) {
            d[k] = dst[i]; s[k] = src[i];
            atomicAdd(&lh[d[k] >> 8], 1);
        } else d[k] = -1;
    }
    __syncthreads();
    for (int j = tid; j < NBUK; j += 256) lbase[j] = lh[j] ? atomicAdd(&bukcur[j], lh[j]) : 0;
    __syncthreads();
    for (int j = tid; j < NBUK; j += 256) lh[j] = 0;
    __syncthreads();
    #pragma unroll
    for (int k = 0; k < 8; ++k) {
        if (d[k] >= 0) {
            int b = d[k] >> 8;
            int loc = atomicAdd(&lh[b], 1);
            pairs[lbase[b] + loc] = ((unsigned int)s[k] << 16) | (unsigned int)(d[k] & 255);
        }
    }
}

// per-bucket fine CSR: row_ptr, col8 (pre-shifted src: col<<3 = uint2-unit row offset),
// dis (one block per bucket)
__global__ __launch_bounds__(256) void local_csr_kernel(const unsigned int* __restrict__ pairs,
                                                        const int* __restrict__ bukoff,
                                                        int* __restrict__ row_ptr,
                                                        int* __restrict__ col8,
                                                        float* __restrict__ dis) {
    __shared__ int fcnt[256];
    __shared__ int foff[256];
    __shared__ int fws[4];
    int b = blockIdx.x, tid = threadIdx.x;
    int beg = bukoff[b], end = bukoff[b + 1];
    fcnt[tid] = 0;
    __syncthreads();
    for (int i = beg + tid; i < end; i += 256) atomicAdd(&fcnt[pairs[i] & 255], 1);
    __syncthreads();
    int lane = tid & 63, wid = tid >> 6;
    int v = fcnt[tid], incl = v;
    #pragma unroll
    for (int off = 1; off < 64; off <<= 1) {
        int u = __shfl_up(incl, off, 64);
        if (lane >= off) incl += u;
    }
    if (lane == 63) fws[wid] = incl;
    __syncthreads();
    int woff = 0;
    for (int w = 0; w < wid; ++w) woff += fws[w];
    int ex = woff + incl - v;  // exclusive fine offset
    foff[tid] = ex;
    int gid = b * 256 + tid;
    if (gid < NN) {
        row_ptr[gid] = beg + ex;
        dis[gid] = rsqrtf((float)v + 1.0f);
    }
    if (b == 0 && tid == 0) row_ptr[NN] = NE;
    __syncthreads();
    // scatter src into col8 using foff as LDS cursors
    for (int i = beg + tid; i < end; i += 256) {
        unsigned int p = pairs[i];
        int loc = atomicAdd(&foff[p & 255], 1);
        col8[beg + loc] = (int)(p >> 16) << 3;
    }
}

// SEGMENT-LOCAL degree sort: one block per 2048-node segment. LDS histogram +
// scan + LDS-cursor scatter -- zero global atomics. perm groups equal-degree
// nodes (wave-uniform trip counts in agg) while keeping each 32-node agg block
// inside a 2048-node window (col8/Out accesses stay in a ~128 KB sliding
// window -> slice table stays L2-resident; fixes round-4's FETCH 27->99 MB blowup).
__global__ __launch_bounds__(256) void segperm_kernel(const int* __restrict__ row_ptr,
                                                      int* __restrict__ perm) {
    __shared__ int hist[256];
    __shared__ int ws[4];
    int tid = threadIdx.x;
    int base = blockIdx.x * SEGSZ;
    int segN = NN - base; if (segN > SEGSZ) segN = SEGSZ;
    hist[tid] = 0;
    __syncthreads();
    int deg[8];
    #pragma unroll
    for (int k = 0; k < 8; ++k) {
        int j = k * 256 + tid;
        if (j < segN) {
            int d = row_ptr[base + j + 1] - row_ptr[base + j];
            if (d > 255) d = 255;
            deg[k] = d;
            atomicAdd(&hist[d], 1);
        } else deg[k] = -1;
    }
    __syncthreads();
    int lane = tid & 63, wid = tid >> 6;
    int v = hist[tid], incl = v;
    #pragma unroll
    for (int off = 1; off < 64; off <<= 1) {
        int u = __shfl_up(incl, off, 64);
        if (lane >= off) incl += u;
    }
    if (lane == 63) ws[wid] = incl;
    __syncthreads();
    int woff = 0;
    for (int w = 0; w < wid; ++w) woff += ws[w];
    hist[tid] = woff + incl - v;  // exclusive offset becomes bin cursor
    __syncthreads();
    #pragma unroll
    for (int k = 0; k < 8; ++k) {
        if (deg[k] >= 0) {
            int rank = atomicAdd(&hist[deg[k]], 1);
            perm[base + rank] = base + k * 256 + tid;
        }
    }
}

// Xb[s][i][f'] = bf16(dis[i] * x[i][f])  -- blocked layout, 4 slices of 32 feats
__global__ void cast_scale_kernel(const float* __restrict__ x, const float* __restrict__ dis,
                                  unsigned short* __restrict__ Xb, int n4) {
    int i = blockIdx.x * 256 + threadIdx.x;  // float4 index over [NN][128]
    if (i < n4) {
        int node = i >> 5;   // 32 float4 per row
        int f4 = i & 31;     // float4 index within row
        int s = f4 >> 3;     // slice = feat>>5
        int o = f4 & 7;      // float4 within the 32-feat slice
        float dv = dis[node];
        float4 v = ((const float4*)x)[i];
        ushort4 w;
        w.x = f2bf(dv * v.x); w.y = f2bf(dv * v.y); w.z = f2bf(dv * v.z); w.w = f2bf(dv * v.w);
        ((ushort4*)Xb)[((size_t)s * NN + (size_t)node) * 8 + o] = w;
    }
}

// all three weights transposed+cast in one dispatch: W [K,256] fp32 -> Wt [256,K] bf16
__global__ void tcast_all_kernel(const float* __restrict__ W1, const float* __restrict__ W2,
                                 const float* __restrict__ W3,
                                 unsigned short* __restrict__ W1t, unsigned short* __restrict__ W2t,
                                 unsigned short* __restrict__ W3t) {
    int idx = blockIdx.x * 256 + threadIdx.x;
    if (idx < FIN * 256) {
        int n = idx / FIN, k = idx - n * FIN;
        W1t[idx] = f2bf(W1[(size_t)k * 256 + n]);
    } else if (idx < FIN * 256 + HID * 256) {
        int t = idx - FIN * 256;
        int n = t / HID, k = t - n * HID;
        W2t[t] = f2bf(W2[(size_t)k * 256 + n]);
    } else {
        int t = idx - FIN * 256 - HID * 256;
        int n = t / HID, k = t - n * HID;
        W3t[t] = f2bf(W3[(size_t)k * 256 + n]);
    }
}

// 128x128 GEMM, BK=32, global_load_lds staging, LDS-bounce coalesced epilogue.
// A:[M,K] bf16 row-major, Bt:[256,K] bf16.
// MODE 0: Hs = bf16(dis[row]*relu(acc + bias[col])) -> BLOCKED [8][M][32] (feeds slice-agg)
// MODE 1: Hf = bf16(relu(acc + bias[col]))          -> row-major [M][256] (feeds pooling)
#define CLD 136   // C-tile LDS row stride in shorts (mult of 8 -> 16B-aligned rows)
template <int MODE>
__global__ __launch_bounds__(256) void gemm128_kernel(
        const unsigned short* __restrict__ A, const unsigned short* __restrict__ Bt,
        const float* __restrict__ dis, const float* __restrict__ bias,
        unsigned short* __restrict__ Cout, int M, int K) {
    __shared__ unsigned short smem[128 * CLD];  // K-loop: As=smem[0:4096], Bs=smem[4096:8192]
    unsigned short* As = smem;
    unsigned short* Bs = smem + 4096;
    const int tid = threadIdx.x;
    const int bm = blockIdx.x * 128, bn = blockIdx.y * 128;
    const int wave = tid >> 6, lane = tid & 63;
    const int l16 = lane & 15, quad = lane >> 4;
    const int wm = (wave & 1) * 64, wn = (wave >> 1) * 64;

    int srow0 = tid >> 2, skc = (tid & 3) * 8;
    int srow1 = (256 + tid) >> 2;
    int ar0 = bm + srow0; if (ar0 > M - 1) ar0 = M - 1;
    int ar1 = bm + srow1; if (ar1 > M - 1) ar1 = M - 1;

    f32x4 acc[4][4];
    #pragma unroll
    for (int i = 0; i < 4; ++i)
        #pragma unroll
        for (int j = 0; j < 4; ++j) acc[i][j] = (f32x4){0.f, 0.f, 0.f, 0.f};

    for (int k0 = 0; k0 < K; k0 += 32) {
        gload16(A + (size_t)ar0 * K + k0 + skc, &As[(size_t)tid * 8]);
        gload16(A + (size_t)ar1 * K + k0 + skc, &As[(size_t)(256 + tid) * 8]);
        gload16(Bt + (size_t)(bn + srow0) * K + k0 + skc, &Bs[(size_t)tid * 8]);
        gload16(Bt + (size_t)(bn + srow1) * K + k0 + skc, &Bs[(size_t)(256 + tid) * 8]);
        __syncthreads();
        short8 af[4], bf[4];
        #pragma unroll
        for (int mt = 0; mt < 4; ++mt) af[mt] = *(const short8*)&As[(wm + mt * 16 + l16) * 32 + quad * 8];
        #pragma unroll
        for (int nt = 0; nt < 4; ++nt) bf[nt] = *(const short8*)&Bs[(wn + nt * 16 + l16) * 32 + quad * 8];
        #pragma unroll
        for (int mt = 0; mt < 4; ++mt)
            #pragma unroll
            for (int nt = 0; nt < 4; ++nt)
                acc[mt][nt] = __builtin_amdgcn_mfma_f32_16x16x32_bf16(af[mt], bf[nt], acc[mt][nt], 0, 0, 0);
        __syncthreads();
    }
    // phase 1: acc -> LDS tile (bf16), bias/relu/dis applied.  C/D: col=l16+16nt+wn, row=quad*4+r+16mt+wm
    float bv[4];
    #pragma unroll
    for (int nt = 0; nt < 4; ++nt) bv[nt] = bias[bn + wn + nt * 16 + l16];
    #pragma unroll
    for (int mt = 0; mt < 4; ++mt) {
        #pragma unroll
        for (int r = 0; r < 4; ++r) {
            int lrow = wm + mt * 16 + quad * 4 + r;
            int grow = bm + lrow; if (grow > M - 1) grow = M - 1;
            float dv = (MODE == 0) ? dis[grow] : 1.0f;
            #pragma unroll
            for (int nt = 0; nt < 4; ++nt) {
                float v = fmaxf(acc[mt][nt][r] + bv[nt], 0.f);
                if (MODE == 0) v *= dv;
                smem[lrow * CLD + wn + nt * 16 + l16] = f2bf(v);
            }
        }
    }
    __syncthreads();
    // phase 2: LDS -> global, 16B coalesced chunks (2048 chunks, 8 per thread)
    for (int c = tid; c < 2048; c += 256) {
        int lrow = c >> 4, coff = (c & 15) << 3;
        int grow = bm + lrow;
        if (grow < M) {
            if (MODE == 0) {
                int gcol = bn + coff;
                int s = gcol >> 5, o = gcol & 31;  // blocked [8][M][32]
                *(u16x8*)(Cout + ((size_t)s * M + (size_t)grow) * 32 + o) =
                    *(const u16x8*)&smem[lrow * CLD + coff];
            } else {
                *(u16x8*)(Cout + (size_t)grow * HID + bn + coff) =
                    *(const u16x8*)&smem[lrow * CLD + coff];
            }
        }
    }
}
#undef CLD

// Feature-slice-blocked aggregation: 8 lanes/node x 8 B (u32x2), segment-degree-sorted.
// In: Hb blocked [S][NN][32] bf16 (slice table 3.2 MB, resident in one XCD's 4 MB L2
//     via slice = bid & (S-1) round-robin pinning).
// perm: nodes grouped by degree within 2048-node segments -> wave-uniform trip counts
//     AND block-local col8/Out windows (~128 KB) so the slice table stays L2-resident.
// Out row-major [NN][S*32]: Out[v] = bf16(dis[v]*(sum_N Hb[u] + Hb[v])).
template <int S>
__global__ __launch_bounds__(256) void agg_slice_kernel(
        const unsigned short* __restrict__ Hb, const int* __restrict__ row_ptr,
        const int* __restrict__ col8, const int* __restrict__ perm,
        const float* __restrict__ dis,
        unsigned short* __restrict__ Out, int n) {
    constexpr int LOGS = (S == 8) ? 3 : 2;
    int bid = blockIdx.x;
    int s = bid & (S - 1);
    int idx = (bid >> LOGS) * 32 + (threadIdx.x >> 3);
    if (idx >= n) return;
    int node = perm[idx];
    int lane8 = threadIdx.x & 7;
    const u32x2* Hv = (const u32x2*)Hb + (size_t)s * NN * 8;
    u32x2 p = Hv[node * 8 + lane8];  // self loop
    f32x2 a01 = {bflo(p.x), bfhi(p.x)};
    f32x2 a23 = {bflo(p.y), bfhi(p.y)};
    int e = row_ptr[node], end = row_ptr[node + 1];
    for (; e + 8 <= end; e += 8) {
        u32x2 m[8];
        #pragma unroll
        for (int j = 0; j < 8; ++j) m[j] = Hv[col8[e + j] + lane8];
        #pragma unroll
        for (int j = 0; j < 8; ++j) {
            f32x2 lo = {bflo(m[j].x), bfhi(m[j].x)};
            f32x2 hi = {bflo(m[j].y), bfhi(m[j].y)};
            a01 = pkadd(a01, lo);
            a23 = pkadd(a23, hi);
        }
    }
    for (; e < end; ++e) {
        u32x2 m = Hv[col8[e] + lane8];
        f32x2 lo = {bflo(m.x), bfhi(m.x)};
        f32x2 hi = {bflo(m.y), bfhi(m.y)};
        a01 = pkadd(a01, lo);
        a23 = pkadd(a23, hi);
    }
    float dv = dis[node];
    u32x2 o;
    o.x = (unsigned int)f2bf(dv * a01.x) | ((unsigned int)f2bf(dv * a01.y) << 16);
    o.y = (unsigned int)f2bf(dv * a23.x) | ((unsigned int)f2bf(dv * a23.y) << 16);
    __builtin_nontemporal_store(o, (u32x2*)Out + (size_t)node * (S * 8) + s * 8 + lane8);
}

// one block per graph: mean-pool (bf16 Hf) + concat + FC1(relu) + FC2
__global__ __launch_bounds__(256) void pool_mlp_kernel(
        const unsigned short* __restrict__ H, const int* __restrict__ goff,
        const float* __restrict__ mol, const float* __restrict__ rings,
        const float* __restrict__ fcW1, const float* __restrict__ fcb1,
        const float* __restrict__ fcW2, const float* __restrict__ fcb2,
        float* __restrict__ out) {
    __shared__ float s_hg[258];
    __shared__ float s_t[196];
    int g = blockIdx.x, tid = threadIdx.x;
    int beg = goff[g], end = goff[g + 1];
    float acc = 0.f;
    for (int i = beg; i < end; ++i) acc += bf2f(H[(size_t)i * HID + tid]);
    s_hg[tid] = acc / fmaxf((float)(end - beg), 1.0f);
    if (tid == 0) { s_hg[256] = mol[g]; s_hg[257] = rings[g]; }
    __syncthreads();
    if (tid < 196) {
        float a = fcb1[tid];
        for (int k = 0; k < 258; ++k) a = fmaf(s_hg[k], fcW1[k * 196 + tid], a);
        s_t[tid] = fmaxf(a, 0.f);
    }
    __syncthreads();
    if (tid < 16) {
        float a = fcb2[tid];
        for (int k = 0; k < 196; ++k) a = fmaf(s_t[k], fcW2[k * 16 + tid], a);
        out[g * 16 + tid] = a;
    }
}

extern "C" void kernel_launch(void* const* d_in, const int* in_sizes, int n_in,
                              void* d_out, int out_size, void* d_ws, size_t ws_size,
                              hipStream_t stream) {
    const float* x     = (const float*)d_in[0];
    const int*   ei    = (const int*)d_in[1];
    const int*   batch = (const int*)d_in[2];
    const float* mol   = (const float*)d_in[3];
    const float* rings = (const float*)d_in[4];
    const float* W1 = (const float*)d_in[5];
    const float* b1 = (const float*)d_in[6];
    const float* W2 = (const float*)d_in[7];
    const float* b2 = (const float*)d_in[8];
    const float* W3 = (const float*)d_in[9];
    const float* b3 = (const float*)d_in[10];
    const float* fcW1 = (const float*)d_in[11];
    const float* fcb1 = (const float*)d_in[12];
    const float* fcW2 = (const float*)d_in[13];
    const float* fcb2 = (const float*)d_in[14];
    float* out = (float*)d_out;
    const int* src = ei;
    const int* dst = ei + NE;

    char* w = (char*)d_ws;
    auto alloc = [&](size_t bytes) {
        char* p = w;
        w += (bytes + 255) & ~(size_t)255;
        return p;
    };
    int*   gbuk    = (int*)alloc((size_t)NBUK * 4);
    int*   bukoff  = (int*)alloc((size_t)(NBUK + 1) * 4);
    int*   bukcur  = (int*)alloc((size_t)NBUK * 4);
    int*   row_ptr = (int*)alloc((size_t)(NN + 1) * 4);
    int*   goff    = (int*)alloc((size_t)(NG + 1) * 4);
    float* dis     = (float*)alloc((size_t)NN * 4);
    int*   perm    = (int*)alloc((size_t)NN * 4);
    unsigned int* pairs = (unsigned int*)alloc((size_t)NE * 4);
    int*   col8    = (int*)alloc((size_t)NE * 4);
    unsigned short* Xs  = (unsigned short*)alloc((size_t)NN * FIN * 2);  // blocked [4][NN][32]
    unsigned short* Xa  = (unsigned short*)alloc((size_t)NN * FIN * 2);  // row-major
    unsigned short* Hs  = (unsigned short*)alloc((size_t)NN * HID * 2);  // blocked [8][NN][32]
    unsigned short* Ga  = (unsigned short*)alloc((size_t)NN * HID * 2);  // row-major
    unsigned short* Hf  = (unsigned short*)alloc((size_t)NN * HID * 2);  // row-major
    unsigned short* W1t = (unsigned short*)alloc((size_t)FIN * HID * 2);
    unsigned short* W2t = (unsigned short*)alloc((size_t)HID * HID * 2);
    unsigned short* W3t = (unsigned short*)alloc((size_t)HID * HID * 2);

    hipMemsetAsync(gbuk, 0, (size_t)NBUK * 4, stream);
    int eb = cdiv(NE, 2048);  // 391
    hist_bucket_kernel<<<eb, 256, 0, stream>>>(dst, gbuk);
    goff_kernel<<<cdiv(NN, 256), 256, 0, stream>>>(batch, goff);
    buk_scan_kernel<<<1, 256, 0, stream>>>(gbuk, bukoff, bukcur);
    scatter_kernel<<<eb, 256, 0, stream>>>(src, dst, bukcur, pairs);
    local_csr_kernel<<<NBUK, 256, 0, stream>>>(pairs, bukoff, row_ptr, col8, dis);
    segperm_kernel<<<cdiv(NN, SEGSZ), 256, 0, stream>>>(row_ptr, perm);

    cast_scale_kernel<<<cdiv(NN * FIN / 4, 256), 256, 0, stream>>>(x, dis, Xs, NN * FIN / 4);
    tcast_all_kernel<<<cdiv((FIN + HID + HID) * 256, 256), 256, 0, stream>>>(W1, W2, W3, W1t, W2t, W3t);

    dim3 ggrid(cdiv(NN, 128), 2);
    int achunks = cdiv(NN, 32);  // 1563
    // all layers: aggregate-then-transform (aggregation commutes with @W)
    agg_slice_kernel<4><<<4 * achunks, 256, 0, stream>>>(Xs, row_ptr, col8, perm, dis, Xa, NN);
    gemm128_kernel<0><<<ggrid, 256, 0, stream>>>(Xa, W1t, dis, b1, Hs, NN, FIN);  // Hs1 blocked
    agg_slice_kernel<8><<<8 * achunks, 256, 0, stream>>>(Hs, row_ptr, col8, perm, dis, Ga, NN);
    gemm128_kernel<0><<<ggrid, 256, 0, stream>>>(Ga, W2t, dis, b2, Hs, NN, HID);  // Hs2 blocked
    agg_slice_kernel<8><<<8 * achunks, 256, 0, stream>>>(Hs, row_ptr, col8, perm, dis, Ga, NN);
    gemm128_kernel<1><<<ggrid, 256, 0, stream>>>(Ga, W3t, dis, b3, Hf, NN, HID);  // Hf row-major
    pool_mlp_kernel<<<NG, 256, 0, stream>>>(Hf, goff, mol, rings, fcW1, fcb1, fcW2, fcb2, out);
}

// Round 7
// 381.405 us; speedup vs baseline: 1.4105x; 1.0208x over previous
//
#include <hip/hip_runtime.h>

#define NN 50000
#define NE 800000
#define NG 512
#define FIN 128
#define HID 256
#define NBUK 196   // buckets of 256 node ids: ceil(50000/256)
#define SEGSZ 2048 // segment size for the locality-preserving degree sort

typedef short short8 __attribute__((ext_vector_type(8)));
typedef float f32x4 __attribute__((ext_vector_type(4)));
typedef float f32x2 __attribute__((ext_vector_type(2)));
typedef unsigned short u16x8 __attribute__((ext_vector_type(8)));
typedef unsigned int u32x2 __attribute__((ext_vector_type(2)));
typedef unsigned int u32x4 __attribute__((ext_vector_type(4)));

static inline int cdiv(int a, int b) { return (a + b - 1) / b; }

static __device__ inline unsigned short f2bf(float f) {
    unsigned int u = __float_as_uint(f);
    unsigned int r = (u + 0x7FFF + ((u >> 16) & 1)) >> 16;  // RNE
    return (unsigned short)r;
}
static __device__ inline float bf2f(unsigned short h) {
    return __uint_as_float(((unsigned int)h) << 16);
}
static __device__ inline float bflo(unsigned int p) { return __uint_as_float(p << 16); }
static __device__ inline float bfhi(unsigned int p) { return __uint_as_float(p & 0xFFFF0000u); }

// packed fp32 add (gfx90a+): 1 instr for 2 lane-local f32 adds
static __device__ __forceinline__ f32x2 pkadd(f32x2 a, f32x2 b) {
    f32x2 r;
    asm("v_pk_add_f32 %0, %1, %2" : "=v"(r) : "v"(a), "v"(b));
    return r;
}

// ds_swizzle broadcast within each 8-lane group: all lanes get lane (group*8+J)'s value.
// BitMode offset: xor=0, or=J, and=0x18 (keep group bits, force low3 = J).
template <int J>
static __device__ __forceinline__ int bswz(int v) {
    return __builtin_amdgcn_ds_swizzle(v, (J << 5) | 0x18);
}

typedef __attribute__((address_space(1))) unsigned int gu32;
typedef __attribute__((address_space(3))) unsigned int lu32;
static __device__ __forceinline__ void gload16(const unsigned short* g, unsigned short* l) {
    __builtin_amdgcn_global_load_lds((const gu32*)(const void*)g, (lu32*)(void*)l, 16, 0, 0);
}

// ---- CSR build, bucket-sort style (no per-edge global atomics) ----

// coarse 196-bucket histogram of dst, LDS-privatized
__global__ __launch_bounds__(256) void hist_bucket_kernel(const int* __restrict__ dst,
                                                          int* __restrict__ gbuk) {
    __shared__ int lh[NBUK];
    int tid = threadIdx.x;
    for (int j = tid; j < NBUK; j += 256) lh[j] = 0;
    __syncthreads();
    int base = blockIdx.x * 2048;
    #pragma unroll
    for (int k = 0; k < 8; ++k) {
        int i = base + k * 256 + tid;
        if (i < NE) atomicAdd(&lh[dst[i] >> 8], 1);
    }
    __syncthreads();
    for (int j = tid; j < NBUK; j += 256) if (lh[j]) atomicAdd(&gbuk[j], lh[j]);
}

// batch is sorted: goff by boundary detection, no atomics
__global__ void goff_kernel(const int* __restrict__ batch, int* __restrict__ goff) {
    int i = blockIdx.x * 256 + threadIdx.x;
    if (i >= NN) return;
    int b = batch[i];
    int pb = (i == 0) ? -1 : batch[i - 1];
    for (int g = pb + 1; g <= b; ++g) goff[g] = i;
    if (i == NN - 1) for (int g = b + 1; g <= NG; ++g) goff[g] = NN;
}

// single-block exclusive scan of gbuk[196] -> bukoff[197], plus cursor copy
__global__ void buk_scan_kernel(const int* __restrict__ gbuk, int* __restrict__ bukoff,
                                int* __restrict__ bukcur) {
    __shared__ int ws[4];
    int tid = threadIdx.x, lane = tid & 63, wid = tid >> 6;
    int v = (tid < NBUK) ? gbuk[tid] : 0;
    int incl = v;
    #pragma unroll
    for (int off = 1; off < 64; off <<= 1) {
        int u = __shfl_up(incl, off, 64);
        if (lane >= off) incl += u;
    }
    if (lane == 63) ws[wid] = incl;
    __syncthreads();
    int woff = 0;
    for (int w = 0; w < wid; ++w) woff += ws[w];
    int ex = woff + incl - v;
    if (tid < NBUK) { bukoff[tid] = ex; bukcur[tid] = ex; }
    if (tid == NBUK - 1) bukoff[NBUK] = ex + v;
}

// scatter edges into bucket-contiguous pairs[]; one global atomic per block per bucket
__global__ __launch_bounds__(256) void scatter_kernel(const int* __restrict__ src,
                                                      const int* __restrict__ dst,
                                                      int* __restrict__ bukcur,
                                                      unsigned int* __restrict__ pairs) {
    __shared__ int lh[NBUK];
    __shared__ int lbase[NBUK];
    int tid = threadIdx.x;
    for (int j = tid; j < NBUK; j += 256) lh[j] = 0;
    __syncthreads();
    int base = blockIdx.x * 2048;
    int d[8], s[8];
    #pragma unroll
    for (int k = 0; k < 8; ++k) {
        int i = base + k * 256 + tid;
        if (i < NE) {
            d[k] = dst[i]; s[k] = src[i];
            atomicAdd(&lh[d[k] >> 8], 1);
        } else d[k] = -1;
    }
    __syncthreads();
    for (int j = tid; j < NBUK; j += 256) lbase[j] = lh[j] ? atomicAdd(&bukcur[j], lh[j]) : 0;
    __syncthreads();
    for (int j = tid; j < NBUK; j += 256) lh[j] = 0;
    __syncthreads();
    #pragma unroll
    for (int k = 0; k < 8; ++k) {
        if (d[k] >= 0) {
            int b = d[k] >> 8;
            int loc = atomicAdd(&lh[b], 1);
            pairs[lbase[b] + loc] = ((unsigned int)s[k] << 16) | (unsigned int)(d[k] & 255);
        }
    }
}

// per-bucket fine CSR: row_ptr, col8 (pre-shifted src: col<<3 = uint2-unit row offset),
// dis (one block per bucket)
__global__ __launch_bounds__(256) void local_csr_kernel(const unsigned int* __restrict__ pairs,
                                                        const int* __restrict__ bukoff,
                                                        int* __restrict__ row_ptr,
                                                        int* __restrict__ col8,
                                                        float* __restrict__ dis) {
    __shared__ int fcnt[256];
    __shared__ int foff[256];
    __shared__ int fws[4];
    int b = blockIdx.x, tid = threadIdx.x;
    int beg = bukoff[b], end = bukoff[b + 1];
    fcnt[tid] = 0;
    __syncthreads();
    for (int i = beg + tid; i < end; i += 256) atomicAdd(&fcnt[pairs[i] & 255], 1);
    __syncthreads();
    int lane = tid & 63, wid = tid >> 6;
    int v = fcnt[tid], incl = v;
    #pragma unroll
    for (int off = 1; off < 64; off <<= 1) {
        int u = __shfl_up(incl, off, 64);
        if (lane >= off) incl += u;
    }
    if (lane == 63) fws[wid] = incl;
    __syncthreads();
    int woff = 0;
    for (int w = 0; w < wid; ++w) woff += fws[w];
    int ex = woff + incl - v;  // exclusive fine offset
    foff[tid] = ex;
    int gid = b * 256 + tid;
    if (gid < NN) {
        row_ptr[gid] = beg + ex;
        dis[gid] = rsqrtf((float)v + 1.0f);
    }
    if (b == 0 && tid == 0) row_ptr[NN] = NE;
    __syncthreads();
    // scatter src into col8 using foff as LDS cursors
    for (int i = beg + tid; i < end; i += 256) {
        unsigned int p = pairs[i];
        int loc = atomicAdd(&foff[p & 255], 1);
        col8[beg + loc] = (int)(p >> 16) << 3;
    }
}

// SEGMENT-LOCAL degree sort -> work DESCRIPTORS. One block per 2048-node segment:
// LDS histogram + scan + LDS-cursor scatter, zero global atomics. Groups equal-degree
// nodes (wave-uniform trip counts) while keeping each agg block inside a 2048-node
// window (slice table stays L2-resident). desc[idx] = {node*8, e_beg, e_end, dis bits}:
// one 16B load replaces the perm->row_ptr->dis dependent chain in every agg pass.
__global__ __launch_bounds__(256) void segperm_kernel(const int* __restrict__ row_ptr,
                                                      const float* __restrict__ dis,
                                                      u32x4* __restrict__ desc) {
    __shared__ int hist[256];
    __shared__ int ws[4];
    int tid = threadIdx.x;
    int base = blockIdx.x * SEGSZ;
    int segN = NN - base; if (segN > SEGSZ) segN = SEGSZ;
    hist[tid] = 0;
    __syncthreads();
    int dbin[8], rb[8], dreal[8];
    #pragma unroll
    for (int k = 0; k < 8; ++k) {
        int j = k * 256 + tid;
        if (j < segN) {
            rb[k] = row_ptr[base + j];
            dreal[k] = row_ptr[base + j + 1] - rb[k];
            int d = dreal[k] > 255 ? 255 : dreal[k];
            dbin[k] = d;
            atomicAdd(&hist[d], 1);
        } else dbin[k] = -1;
    }
    __syncthreads();
    int lane = tid & 63, wid = tid >> 6;
    int v = hist[tid], incl = v;
    #pragma unroll
    for (int off = 1; off < 64; off <<= 1) {
        int u = __shfl_up(incl, off, 64);
        if (lane >= off) incl += u;
    }
    if (lane == 63) ws[wid] = incl;
    __syncthreads();
    int woff = 0;
    for (int w = 0; w < wid; ++w) woff += ws[w];
    __syncthreads();
    hist[tid] = woff + incl - v;  // exclusive offset becomes bin cursor
    __syncthreads();
    #pragma unroll
    for (int k = 0; k < 8; ++k) {
        if (dbin[k] >= 0) {
            int rank = atomicAdd(&hist[dbin[k]], 1);
            int node = base + k * 256 + tid;
            u32x4 dd;
            dd.x = (unsigned int)(node * 8);
            dd.y = (unsigned int)rb[k];
            dd.z = (unsigned int)(rb[k] + dreal[k]);
            dd.w = __float_as_uint(dis[node]);
            desc[base + rank] = dd;
        }
    }
}

// Xb[s][i][f'] = bf16(dis[i] * x[i][f])  -- blocked layout, 4 slices of 32 feats
__global__ void cast_scale_kernel(const float* __restrict__ x, const float* __restrict__ dis,
                                  unsigned short* __restrict__ Xb, int n4) {
    int i = blockIdx.x * 256 + threadIdx.x;  // float4 index over [NN][128]
    if (i < n4) {
        int node = i >> 5;   // 32 float4 per row
        int f4 = i & 31;     // float4 index within row
        int s = f4 >> 3;     // slice = feat>>5
        int o = f4 & 7;      // float4 within the 32-feat slice
        float dv = dis[node];
        float4 v = ((const float4*)x)[i];
        ushort4 w;
        w.x = f2bf(dv * v.x); w.y = f2bf(dv * v.y); w.z = f2bf(dv * v.z); w.w = f2bf(dv * v.w);
        ((ushort4*)Xb)[((size_t)s * NN + (size_t)node) * 8 + o] = w;
    }
}

// all three weights transposed+cast in one dispatch: W [K,256] fp32 -> Wt [256,K] bf16
__global__ void tcast_all_kernel(const float* __restrict__ W1, const float* __restrict__ W2,
                                 const float* __restrict__ W3,
                                 unsigned short* __restrict__ W1t, unsigned short* __restrict__ W2t,
                                 unsigned short* __restrict__ W3t) {
    int idx = blockIdx.x * 256 + threadIdx.x;
    if (idx < FIN * 256) {
        int n = idx / FIN, k = idx - n * FIN;
        W1t[idx] = f2bf(W1[(size_t)k * 256 + n]);
    } else if (idx < FIN * 256 + HID * 256) {
        int t = idx - FIN * 256;
        int n = t / HID, k = t - n * HID;
        W2t[t] = f2bf(W2[(size_t)k * 256 + n]);
    } else {
        int t = idx - FIN * 256 - HID * 256;
        int n = t / HID, k = t - n * HID;
        W3t[t] = f2bf(W3[(size_t)k * 256 + n]);
    }
}

// 128x128 GEMM, BK=32, global_load_lds staging, LDS-bounce coalesced epilogue.
// A:[M,K] bf16 row-major, Bt:[256,K] bf16.
// MODE 0: Hs = bf16(dis[row]*relu(acc + bias[col])) -> BLOCKED [8][M][32] (feeds slice-agg)
// MODE 1: Hf = bf16(relu(acc + bias[col]))          -> row-major [M][256] (feeds pooling)
#define CLD 136   // C-tile LDS row stride in shorts (mult of 8 -> 16B-aligned rows)
template <int MODE>
__global__ __launch_bounds__(256) void gemm128_kernel(
        const unsigned short* __restrict__ A, const unsigned short* __restrict__ Bt,
        const float* __restrict__ dis, const float* __restrict__ bias,
        unsigned short* __restrict__ Cout, int M, int K) {
    __shared__ unsigned short smem[128 * CLD];  // K-loop: As=smem[0:4096], Bs=smem[4096:8192]
    unsigned short* As = smem;
    unsigned short* Bs = smem + 4096;
    const int tid = threadIdx.x;
    const int bm = blockIdx.x * 128, bn = blockIdx.y * 128;
    const int wave = tid >> 6, lane = tid & 63;
    const int l16 = lane & 15, quad = lane >> 4;
    const int wm = (wave & 1) * 64, wn = (wave >> 1) * 64;

    int srow0 = tid >> 2, skc = (tid & 3) * 8;
    int srow1 = (256 + tid) >> 2;
    int ar0 = bm + srow0; if (ar0 > M - 1) ar0 = M - 1;
    int ar1 = bm + srow1; if (ar1 > M - 1) ar1 = M - 1;

    f32x4 acc[4][4];
    #pragma unroll
    for (int i = 0; i < 4; ++i)
        #pragma unroll
        for (int j = 0; j < 4; ++j) acc[i][j] = (f32x4){0.f, 0.f, 0.f, 0.f};

    for (int k0 = 0; k0 < K; k0 += 32) {
        gload16(A + (size_t)ar0 * K + k0 + skc, &As[(size_t)tid * 8]);
        gload16(A + (size_t)ar1 * K + k0 + skc, &As[(size_t)(256 + tid) * 8]);
        gload16(Bt + (size_t)(bn + srow0) * K + k0 + skc, &Bs[(size_t)tid * 8]);
        gload16(Bt + (size_t)(bn + srow1) * K + k0 + skc, &Bs[(size_t)(256 + tid) * 8]);
        __syncthreads();
        short8 af[4], bf[4];
        #pragma unroll
        for (int mt = 0; mt < 4; ++mt) af[mt] = *(const short8*)&As[(wm + mt * 16 + l16) * 32 + quad * 8];
        #pragma unroll
        for (int nt = 0; nt < 4; ++nt) bf[nt] = *(const short8*)&Bs[(wn + nt * 16 + l16) * 32 + quad * 8];
        #pragma unroll
        for (int mt = 0; mt < 4; ++mt)
            #pragma unroll
            for (int nt = 0; nt < 4; ++nt)
                acc[mt][nt] = __builtin_amdgcn_mfma_f32_16x16x32_bf16(af[mt], bf[nt], acc[mt][nt], 0, 0, 0);
        __syncthreads();
    }
    // phase 1: acc -> LDS tile (bf16), bias/relu/dis applied.  C/D: col=l16+16nt+wn, row=quad*4+r+16mt+wm
    float bv[4];
    #pragma unroll
    for (int nt = 0; nt < 4; ++nt) bv[nt] = bias[bn + wn + nt * 16 + l16];
    #pragma unroll
    for (int mt = 0; mt < 4; ++mt) {
        #pragma unroll
        for (int r = 0; r < 4; ++r) {
            int lrow = wm + mt * 16 + quad * 4 + r;
            int grow = bm + lrow; if (grow > M - 1) grow = M - 1;
            float dv = (MODE == 0) ? dis[grow] : 1.0f;
            #pragma unroll
            for (int nt = 0; nt < 4; ++nt) {
                float v = fmaxf(acc[mt][nt][r] + bv[nt], 0.f);
                if (MODE == 0) v *= dv;
                smem[lrow * CLD + wn + nt * 16 + l16] = f2bf(v);
            }
        }
    }
    __syncthreads();
    // phase 2: LDS -> global, 16B coalesced chunks (2048 chunks, 8 per thread)
    for (int c = tid; c < 2048; c += 256) {
        int lrow = c >> 4, coff = (c & 15) << 3;
        int grow = bm + lrow;
        if (grow < M) {
            if (MODE == 0) {
                int gcol = bn + coff;
                int s = gcol >> 5, o = gcol & 31;  // blocked [8][M][32]
                *(u16x8*)(Cout + ((size_t)s * M + (size_t)grow) * 32 + o) =
                    *(const u16x8*)&smem[lrow * CLD + coff];
            } else {
                *(u16x8*)(Cout + (size_t)grow * HID + bn + coff) =
                    *(const u16x8*)&smem[lrow * CLD + coff];
            }
        }
    }
}
#undef CLD

// Feature-slice-blocked aggregation v3: 8 lanes/node x 8 B, desc-driven, swizzle-broadcast col.
// In: Hb blocked [S][NN][32] bf16 (slice table 3.2 MB, L2-resident via slice = bid&(S-1)
//     XCD pinning + segment-local degree sort).
// Per 8-edge iteration: ONE col8 vmem load (lane l reads col8[e+l], consecutive -> 1 line/group)
// + 8 ds_swizzle broadcasts (template-constant pattern) + 8 gathers.
// 9 vmem instr/iter vs 16 before; col line-requests cut 8x.
// desc: {node*8, e_beg, e_end, dis bits} -- one 16B load, no dependent-load chain.
template <int S>
__global__ __launch_bounds__(256) void agg_slice_kernel(
        const unsigned short* __restrict__ Hb, const u32x4* __restrict__ desc,
        const int* __restrict__ col8,
        unsigned short* __restrict__ Out, int n) {
    constexpr int LOGS = (S == 8) ? 3 : 2;
    int bid = blockIdx.x;
    int s = bid & (S - 1);
    int idx = (bid >> LOGS) * 32 + (threadIdx.x >> 3);
    if (idx >= n) return;
    int lane8 = threadIdx.x & 7;
    u32x4 d = desc[idx];
    int node8 = (int)d.x;
    int e = (int)d.y, eend = (int)d.z;
    float dv = __uint_as_float(d.w);
    const u32x2* Hv = (const u32x2*)Hb + (size_t)s * NN * 8;
    u32x2 p = Hv[node8 + lane8];  // self loop
    f32x2 a01 = {bflo(p.x), bfhi(p.x)};
    f32x2 a23 = {bflo(p.y), bfhi(p.y)};
    int nfull = (eend - e) >> 3;
    if (nfull > 0) {
        int cv = col8[e + lane8];
        for (int it = 0; it < nfull; ++it) {
            int cvc = cv;
            if (it + 1 < nfull) cv = col8[e + 8 + lane8];  // prefetch next col vector
            u32x2 m[8];
#define GATH(J) m[J] = Hv[bswz<J>(cvc) + lane8];
            GATH(0) GATH(1) GATH(2) GATH(3) GATH(4) GATH(5) GATH(6) GATH(7)
#undef GATH
            #pragma unroll
            for (int j = 0; j < 8; ++j) {
                f32x2 lo = {bflo(m[j].x), bfhi(m[j].x)};
                f32x2 hi = {bflo(m[j].y), bfhi(m[j].y)};
                a01 = pkadd(a01, lo);
                a23 = pkadd(a23, hi);
            }
            e += 8;
        }
    }
    for (; e < eend; ++e) {
        u32x2 m = Hv[col8[e] + lane8];
        f32x2 lo = {bflo(m.x), bfhi(m.x)};
        f32x2 hi = {bflo(m.y), bfhi(m.y)};
        a01 = pkadd(a01, lo);
        a23 = pkadd(a23, hi);
    }
    int node = node8 >> 3;
    u32x2 o;
    o.x = (unsigned int)f2bf(dv * a01.x) | ((unsigned int)f2bf(dv * a01.y) << 16);
    o.y = (unsigned int)f2bf(dv * a23.x) | ((unsigned int)f2bf(dv * a23.y) << 16);
    __builtin_nontemporal_store(o, (u32x2*)Out + (size_t)node * (S * 8) + s * 8 + lane8);
}

// one block per graph: mean-pool (bf16 Hf) + concat + FC1(relu) + FC2
__global__ __launch_bounds__(256) void pool_mlp_kernel(
        const unsigned short* __restrict__ H, const int* __restrict__ goff,
        const float* __restrict__ mol, const float* __restrict__ rings,
        const float* __restrict__ fcW1, const float* __restrict__ fcb1,
        const float* __restrict__ fcW2, const float* __restrict__ fcb2,
        float* __restrict__ out) {
    __shared__ float s_hg[258];
    __shared__ float s_t[196];
    int g = blockIdx.x, tid = threadIdx.x;
    int beg = goff[g], end = goff[g + 1];
    float acc = 0.f;
    for (int i = beg; i < end; ++i) acc += bf2f(H[(size_t)i * HID + tid]);
    s_hg[tid] = acc / fmaxf((float)(end - beg), 1.0f);
    if (tid == 0) { s_hg[256] = mol[g]; s_hg[257] = rings[g]; }
    __syncthreads();
    if (tid < 196) {
        float a = fcb1[tid];
        for (int k = 0; k < 258; ++k) a = fmaf(s_hg[k], fcW1[k * 196 + tid], a);
        s_t[tid] = fmaxf(a, 0.f);
    }
    __syncthreads();
    if (tid < 16) {
        float a = fcb2[tid];
        for (int k = 0; k < 196; ++k) a = fmaf(s_t[k], fcW2[k * 16 + tid], a);
        out[g * 16 + tid] = a;
    }
}

extern "C" void kernel_launch(void* const* d_in, const int* in_sizes, int n_in,
                              void* d_out, int out_size, void* d_ws, size_t ws_size,
                              hipStream_t stream) {
    const float* x     = (const float*)d_in[0];
    const int*   ei    = (const int*)d_in[1];
    const int*   batch = (const int*)d_in[2];
    const float* mol   = (const float*)d_in[3];
    const float* rings = (const float*)d_in[4];
    const float* W1 = (const float*)d_in[5];
    const float* b1 = (const float*)d_in[6];
    const float* W2 = (const float*)d_in[7];
    const float* b2 = (const float*)d_in[8];
    const float* W3 = (const float*)d_in[9];
    const float* b3 = (const float*)d_in[10];
    const float* fcW1 = (const float*)d_in[11];
    const float* fcb1 = (const float*)d_in[12];
    const float* fcW2 = (const float*)d_in[13];
    const float* fcb2 = (const float*)d_in[14];
    float* out = (float*)d_out;
    const int* src = ei;
    const int* dst = ei + NE;

    char* w = (char*)d_ws;
    auto alloc = [&](size_t bytes) {
        char* p = w;
        w += (bytes + 255) & ~(size_t)255;
        return p;
    };
    int*   gbuk    = (int*)alloc((size_t)NBUK * 4);
    int*   bukoff  = (int*)alloc((size_t)(NBUK + 1) * 4);
    int*   bukcur  = (int*)alloc((size_t)NBUK * 4);
    int*   row_ptr = (int*)alloc((size_t)(NN + 1) * 4);
    int*   goff    = (int*)alloc((size_t)(NG + 1) * 4);
    float* dis     = (float*)alloc((size_t)NN * 4);
    u32x4* desc    = (u32x4*)alloc((size_t)NN * 16);
    unsigned int* pairs = (unsigned int*)alloc((size_t)NE * 4);
    int*   col8    = (int*)alloc((size_t)NE * 4);
    unsigned short* Xs  = (unsigned short*)alloc((size_t)NN * FIN * 2);  // blocked [4][NN][32]
    unsigned short* Xa  = (unsigned short*)alloc((size_t)NN * FIN * 2);  // row-major
    unsigned short* Hs  = (unsigned short*)alloc((size_t)NN * HID * 2);  // blocked [8][NN][32]
    unsigned short* Ga  = (unsigned short*)alloc((size_t)NN * HID * 2);  // row-major
    unsigned short* Hf  = (unsigned short*)alloc((size_t)NN * HID * 2);  // row-major
    unsigned short* W1t = (unsigned short*)alloc((size_t)FIN * HID * 2);
    unsigned short* W2t = (unsigned short*)alloc((size_t)HID * HID * 2);
    unsigned short* W3t = (unsigned short*)alloc((size_t)HID * HID * 2);

    hipMemsetAsync(gbuk, 0, (size_t)NBUK * 4, stream);
    int eb = cdiv(NE, 2048);  // 391
    hist_bucket_kernel<<<eb, 256, 0, stream>>>(dst, gbuk);
    goff_kernel<<<cdiv(NN, 256), 256, 0, stream>>>(batch, goff);
    buk_scan_kernel<<<1, 256, 0, stream>>>(gbuk, bukoff, bukcur);
    scatter_kernel<<<eb, 256, 0, stream>>>(src, dst, bukcur, pairs);
    local_csr_kernel<<<NBUK, 256, 0, stream>>>(pairs, bukoff, row_ptr, col8, dis);
    segperm_kernel<<<cdiv(NN, SEGSZ), 256, 0, stream>>>(row_ptr, dis, desc);

    cast_scale_kernel<<<cdiv(NN * FIN / 4, 256), 256, 0, stream>>>(x, dis, Xs, NN * FIN / 4);
    tcast_all_kernel<<<cdiv((FIN + HID + HID) * 256, 256), 256, 0, stream>>>(W1, W2, W3, W1t, W2t, W3t);

    dim3 ggrid(cdiv(NN, 128), 2);
    int achunks = cdiv(NN, 32);  // 1563
    // all layers: aggregate-then-transform (aggregation commutes with @W)
    agg_slice_kernel<4><<<4 * achunks, 256, 0, stream>>>(Xs, desc, col8, Xa, NN);
    gemm128_kernel<0><<<ggrid, 256, 0, stream>>>(Xa, W1t, dis, b1, Hs, NN, FIN);  // Hs1 blocked
    agg_slice_kernel<8><<<8 * achunks, 256, 0, stream>>>(Hs, desc, col8, Ga, NN);
    gemm128_kernel<0><<<ggrid, 256, 0, stream>>>(Ga, W2t, dis, b2, Hs, NN, HID);  // Hs2 blocked
    agg_slice_kernel<8><<<8 * achunks, 256, 0, stream>>>(Hs, desc, col8, Ga, NN);
    gemm128_kernel<1><<<ggrid, 256, 0, stream>>>(Ga, W3t, dis, b3, Hf, NN, HID);  // Hf row-major
    pool_mlp_kernel<<<NG, 256, 0, stream>>>(Hf, goff, mol, rings, fcW1, fcb1, fcW2, fcb2, out);
}

// Round 8
// 365.583 us; speedup vs baseline: 1.4716x; 1.0433x over previous
//
#include <hip/hip_runtime.h>

#define NN 50000
#define NE 800000
#define NG 512
#define FIN 128
#define HID 256
#define NBUK 196   // buckets of 256 node ids: ceil(50000/256)
#define SEGSZ 2048 // segment size for the locality-preserving degree sort

typedef short short8 __attribute__((ext_vector_type(8)));
typedef float f32x4 __attribute__((ext_vector_type(4)));
typedef float f32x2 __attribute__((ext_vector_type(2)));
typedef unsigned short u16x8 __attribute__((ext_vector_type(8)));
typedef unsigned int u32x2 __attribute__((ext_vector_type(2)));
typedef unsigned int u32x4 __attribute__((ext_vector_type(4)));

static inline int cdiv(int a, int b) { return (a + b - 1) / b; }

static __device__ inline unsigned short f2bf(float f) {
    unsigned int u = __float_as_uint(f);
    unsigned int r = (u + 0x7FFF + ((u >> 16) & 1)) >> 16;  // RNE
    return (unsigned short)r;
}
static __device__ inline float bf2f(unsigned short h) {
    return __uint_as_float(((unsigned int)h) << 16);
}
static __device__ inline float bflo(unsigned int p) { return __uint_as_float(p << 16); }
static __device__ inline float bfhi(unsigned int p) { return __uint_as_float(p & 0xFFFF0000u); }

// packed fp32 add (gfx90a+): 1 instr for 2 lane-local f32 adds
static __device__ __forceinline__ f32x2 pkadd(f32x2 a, f32x2 b) {
    f32x2 r;
    asm("v_pk_add_f32 %0, %1, %2" : "=v"(r) : "v"(a), "v"(b));
    return r;
}

// ds_swizzle broadcast within each 8-lane group: all lanes get lane (group*8+J)'s value.
// BitMode offset: xor=0, or=J, and=0x18 (keep group bits, force low3 = J).
template <int J>
static __device__ __forceinline__ int bswz(int v) {
    return __builtin_amdgcn_ds_swizzle(v, (J << 5) | 0x18);
}

typedef __attribute__((address_space(1))) unsigned int gu32;
typedef __attribute__((address_space(3))) unsigned int lu32;
static __device__ __forceinline__ void gload16(const unsigned short* g, unsigned short* l) {
    __builtin_amdgcn_global_load_lds((const gu32*)(const void*)g, (lu32*)(void*)l, 16, 0, 0);
}

// ---- CSR build, bucket-sort style (no per-edge global atomics) ----

// coarse 196-bucket histogram of dst, LDS-privatized
__global__ __launch_bounds__(256) void hist_bucket_kernel(const int* __restrict__ dst,
                                                          int* __restrict__ gbuk) {
    __shared__ int lh[NBUK];
    int tid = threadIdx.x;
    for (int j = tid; j < NBUK; j += 256) lh[j] = 0;
    __syncthreads();
    int base = blockIdx.x * 2048;
    #pragma unroll
    for (int k = 0; k < 8; ++k) {
        int i = base + k * 256 + tid;
        if (i < NE) atomicAdd(&lh[dst[i] >> 8], 1);
    }
    __syncthreads();
    for (int j = tid; j < NBUK; j += 256) if (lh[j]) atomicAdd(&gbuk[j], lh[j]);
}

// batch is sorted: goff by boundary detection, no atomics
__global__ void goff_kernel(const int* __restrict__ batch, int* __restrict__ goff) {
    int i = blockIdx.x * 256 + threadIdx.x;
    if (i >= NN) return;
    int b = batch[i];
    int pb = (i == 0) ? -1 : batch[i - 1];
    for (int g = pb + 1; g <= b; ++g) goff[g] = i;
    if (i == NN - 1) for (int g = b + 1; g <= NG; ++g) goff[g] = NN;
}

// single-block exclusive scan of gbuk[196] -> bukoff[197], plus cursor copy
__global__ void buk_scan_kernel(const int* __restrict__ gbuk, int* __restrict__ bukoff,
                                int* __restrict__ bukcur) {
    __shared__ int ws[4];
    int tid = threadIdx.x, lane = tid & 63, wid = tid >> 6;
    int v = (tid < NBUK) ? gbuk[tid] : 0;
    int incl = v;
    #pragma unroll
    for (int off = 1; off < 64; off <<= 1) {
        int u = __shfl_up(incl, off, 64);
        if (lane >= off) incl += u;
    }
    if (lane == 63) ws[wid] = incl;
    __syncthreads();
    int woff = 0;
    for (int w = 0; w < wid; ++w) woff += ws[w];
    int ex = woff + incl - v;
    if (tid < NBUK) { bukoff[tid] = ex; bukcur[tid] = ex; }
    if (tid == NBUK - 1) bukoff[NBUK] = ex + v;
}

// scatter edges into bucket-contiguous pairs[]; one global atomic per block per bucket
__global__ __launch_bounds__(256) void scatter_kernel(const int* __restrict__ src,
                                                      const int* __restrict__ dst,
                                                      int* __restrict__ bukcur,
                                                      unsigned int* __restrict__ pairs) {
    __shared__ int lh[NBUK];
    __shared__ int lbase[NBUK];
    int tid = threadIdx.x;
    for (int j = tid; j < NBUK; j += 256) lh[j] = 0;
    __syncthreads();
    int base = blockIdx.x * 2048;
    int d[8], s[8];
    #pragma unroll
    for (int k = 0; k < 8; ++k) {
        int i = base + k * 256 + tid;
        if (i < NE) {
            d[k] = dst[i]; s[k] = src[i];
            atomicAdd(&lh[d[k] >> 8], 1);
        } else d[k] = -1;
    }
    __syncthreads();
    for (int j = tid; j < NBUK; j += 256) lbase[j] = lh[j] ? atomicAdd(&bukcur[j], lh[j]) : 0;
    __syncthreads();
    for (int j = tid; j < NBUK; j += 256) lh[j] = 0;
    __syncthreads();
    #pragma unroll
    for (int k = 0; k < 8; ++k) {
        if (d[k] >= 0) {
            int b = d[k] >> 8;
            int loc = atomicAdd(&lh[b], 1);
            pairs[lbase[b] + loc] = ((unsigned int)s[k] << 16) | (unsigned int)(d[k] & 255);
        }
    }
}

// per-bucket fine CSR: row_ptr, col8 (pre-shifted src: col<<3 = uint2-unit row offset),
// dis (one block per bucket)
__global__ __launch_bounds__(256) void local_csr_kernel(const unsigned int* __restrict__ pairs,
                                                        const int* __restrict__ bukoff,
                                                        int* __restrict__ row_ptr,
                                                        int* __restrict__ col8,
                                                        float* __restrict__ dis) {
    __shared__ int fcnt[256];
    __shared__ int foff[256];
    __shared__ int fws[4];
    int b = blockIdx.x, tid = threadIdx.x;
    int beg = bukoff[b], end = bukoff[b + 1];
    fcnt[tid] = 0;
    __syncthreads();
    for (int i = beg + tid; i < end; i += 256) atomicAdd(&fcnt[pairs[i] & 255], 1);
    __syncthreads();
    int lane = tid & 63, wid = tid >> 6;
    int v = fcnt[tid], incl = v;
    #pragma unroll
    for (int off = 1; off < 64; off <<= 1) {
        int u = __shfl_up(incl, off, 64);
        if (lane >= off) incl += u;
    }
    if (lane == 63) fws[wid] = incl;
    __syncthreads();
    int woff = 0;
    for (int w = 0; w < wid; ++w) woff += fws[w];
    int ex = woff + incl - v;  // exclusive fine offset
    foff[tid] = ex;
    int gid = b * 256 + tid;
    if (gid < NN) {
        row_ptr[gid] = beg + ex;
        dis[gid] = rsqrtf((float)v + 1.0f);
    }
    if (b == 0 && tid == 0) row_ptr[NN] = NE;
    __syncthreads();
    // scatter src into col8 using foff as LDS cursors
    for (int i = beg + tid; i < end; i += 256) {
        unsigned int p = pairs[i];
        int loc = atomicAdd(&foff[p & 255], 1);
        col8[beg + loc] = (int)(p >> 16) << 3;
    }
}

// SEGMENT-LOCAL degree sort -> work DESCRIPTORS. One block per 2048-node segment:
// LDS histogram + scan + LDS-cursor scatter, zero global atomics. Groups equal-degree
// nodes (wave-uniform trip counts) while keeping each agg block inside a 2048-node
// window (slice table stays L2-resident). desc[idx] = {node*8, e_beg, e_end, dis bits}:
// one 16B load replaces the perm->row_ptr->dis dependent chain in every agg pass.
__global__ __launch_bounds__(256) void segperm_kernel(const int* __restrict__ row_ptr,
                                                      const float* __restrict__ dis,
                                                      u32x4* __restrict__ desc) {
    __shared__ int hist[256];
    __shared__ int ws[4];
    int tid = threadIdx.x;
    int base = blockIdx.x * SEGSZ;
    int segN = NN - base; if (segN > SEGSZ) segN = SEGSZ;
    hist[tid] = 0;
    __syncthreads();
    int dbin[8], rb[8], dreal[8];
    #pragma unroll
    for (int k = 0; k < 8; ++k) {
        int j = k * 256 + tid;
        if (j < segN) {
            rb[k] = row_ptr[base + j];
            dreal[k] = row_ptr[base + j + 1] - rb[k];
            int d = dreal[k] > 255 ? 255 : dreal[k];
            dbin[k] = d;
            atomicAdd(&hist[d], 1);
        } else dbin[k] = -1;
    }
    __syncthreads();
    int lane = tid & 63, wid = tid >> 6;
    int v = hist[tid], incl = v;
    #pragma unroll
    for (int off = 1; off < 64; off <<= 1) {
        int u = __shfl_up(incl, off, 64);
        if (lane >= off) incl += u;
    }
    if (lane == 63) ws[wid] = incl;
    __syncthreads();
    int woff = 0;
    for (int w = 0; w < wid; ++w) woff += ws[w];
    __syncthreads();
    hist[tid] = woff + incl - v;  // exclusive offset becomes bin cursor
    __syncthreads();
    #pragma unroll
    for (int k = 0; k < 8; ++k) {
        if (dbin[k] >= 0) {
            int rank = atomicAdd(&hist[dbin[k]], 1);
            int node = base + k * 256 + tid;
            u32x4 dd;
            dd.x = (unsigned int)(node * 8);
            dd.y = (unsigned int)rb[k];
            dd.z = (unsigned int)(rb[k] + dreal[k]);
            dd.w = __float_as_uint(dis[node]);
            desc[base + rank] = dd;
        }
    }
}

// Xb[s][i][f'] = bf16(dis[i] * x[i][f])  -- blocked layout, 4 slices of 32 feats
__global__ void cast_scale_kernel(const float* __restrict__ x, const float* __restrict__ dis,
                                  unsigned short* __restrict__ Xb, int n4) {
    int i = blockIdx.x * 256 + threadIdx.x;  // float4 index over [NN][128]
    if (i < n4) {
        int node = i >> 5;   // 32 float4 per row
        int f4 = i & 31;     // float4 index within row
        int s = f4 >> 3;     // slice = feat>>5
        int o = f4 & 7;      // float4 within the 32-feat slice
        float dv = dis[node];
        float4 v = ((const float4*)x)[i];
        ushort4 w;
        w.x = f2bf(dv * v.x); w.y = f2bf(dv * v.y); w.z = f2bf(dv * v.z); w.w = f2bf(dv * v.w);
        ((ushort4*)Xb)[((size_t)s * NN + (size_t)node) * 8 + o] = w;
    }
}

// all three weights transposed+cast in one dispatch: W [K,256] fp32 -> Wt [256,K] bf16
__global__ void tcast_all_kernel(const float* __restrict__ W1, const float* __restrict__ W2,
                                 const float* __restrict__ W3,
                                 unsigned short* __restrict__ W1t, unsigned short* __restrict__ W2t,
                                 unsigned short* __restrict__ W3t) {
    int idx = blockIdx.x * 256 + threadIdx.x;
    if (idx < FIN * 256) {
        int n = idx / FIN, k = idx - n * FIN;
        W1t[idx] = f2bf(W1[(size_t)k * 256 + n]);
    } else if (idx < FIN * 256 + HID * 256) {
        int t = idx - FIN * 256;
        int n = t / HID, k = t - n * HID;
        W2t[t] = f2bf(W2[(size_t)k * 256 + n]);
    } else {
        int t = idx - FIN * 256 - HID * 256;
        int n = t / HID, k = t - n * HID;
        W3t[t] = f2bf(W3[(size_t)k * 256 + n]);
    }
}

// 128x128 GEMM, BK=32, global_load_lds staging, LDS-bounce coalesced epilogue.
// A:[M,K] bf16 row-major, Bt:[256,K] bf16.
// MODE 0: Hs = bf16(dis[row]*relu(acc + bias[col])) -> BLOCKED [8][M][32] (feeds slice-agg)
// MODE 1: Hf = bf16(relu(acc + bias[col]))          -> row-major [M][256] (feeds pooling)
#define CLD 136   // C-tile LDS row stride in shorts (mult of 8 -> 16B-aligned rows)
template <int MODE>
__global__ __launch_bounds__(256) void gemm128_kernel(
        const unsigned short* __restrict__ A, const unsigned short* __restrict__ Bt,
        const float* __restrict__ dis, const float* __restrict__ bias,
        unsigned short* __restrict__ Cout, int M, int K) {
    __shared__ unsigned short smem[128 * CLD];  // K-loop: As=smem[0:4096], Bs=smem[4096:8192]
    unsigned short* As = smem;
    unsigned short* Bs = smem + 4096;
    const int tid = threadIdx.x;
    const int bm = blockIdx.x * 128, bn = blockIdx.y * 128;
    const int wave = tid >> 6, lane = tid & 63;
    const int l16 = lane & 15, quad = lane >> 4;
    const int wm = (wave & 1) * 64, wn = (wave >> 1) * 64;

    int srow0 = tid >> 2, skc = (tid & 3) * 8;
    int srow1 = (256 + tid) >> 2;
    int ar0 = bm + srow0; if (ar0 > M - 1) ar0 = M - 1;
    int ar1 = bm + srow1; if (ar1 > M - 1) ar1 = M - 1;

    f32x4 acc[4][4];
    #pragma unroll
    for (int i = 0; i < 4; ++i)
        #pragma unroll
        for (int j = 0; j < 4; ++j) acc[i][j] = (f32x4){0.f, 0.f, 0.f, 0.f};

    for (int k0 = 0; k0 < K; k0 += 32) {
        gload16(A + (size_t)ar0 * K + k0 + skc, &As[(size_t)tid * 8]);
        gload16(A + (size_t)ar1 * K + k0 + skc, &As[(size_t)(256 + tid) * 8]);
        gload16(Bt + (size_t)(bn + srow0) * K + k0 + skc, &Bs[(size_t)tid * 8]);
        gload16(Bt + (size_t)(bn + srow1) * K + k0 + skc, &Bs[(size_t)(256 + tid) * 8]);
        __syncthreads();
        short8 af[4], bf[4];
        #pragma unroll
        for (int mt = 0; mt < 4; ++mt) af[mt] = *(const short8*)&As[(wm + mt * 16 + l16) * 32 + quad * 8];
        #pragma unroll
        for (int nt = 0; nt < 4; ++nt) bf[nt] = *(const short8*)&Bs[(wn + nt * 16 + l16) * 32 + quad * 8];
        #pragma unroll
        for (int mt = 0; mt < 4; ++mt)
            #pragma unroll
            for (int nt = 0; nt < 4; ++nt)
                acc[mt][nt] = __builtin_amdgcn_mfma_f32_16x16x32_bf16(af[mt], bf[nt], acc[mt][nt], 0, 0, 0);
        __syncthreads();
    }
    // phase 1: acc -> LDS tile (bf16), bias/relu/dis applied.  C/D: col=l16+16nt+wn, row=quad*4+r+16mt+wm
    float bv[4];
    #pragma unroll
    for (int nt = 0; nt < 4; ++nt) bv[nt] = bias[bn + wn + nt * 16 + l16];
    #pragma unroll
    for (int mt = 0; mt < 4; ++mt) {
        #pragma unroll
        for (int r = 0; r < 4; ++r) {
            int lrow = wm + mt * 16 + quad * 4 + r;
            int grow = bm + lrow; if (grow > M - 1) grow = M - 1;
            float dv = (MODE == 0) ? dis[grow] : 1.0f;
            #pragma unroll
            for (int nt = 0; nt < 4; ++nt) {
                float v = fmaxf(acc[mt][nt][r] + bv[nt], 0.f);
                if (MODE == 0) v *= dv;
                smem[lrow * CLD + wn + nt * 16 + l16] = f2bf(v);
            }
        }
    }
    __syncthreads();
    // phase 2: LDS -> global, 16B coalesced chunks (2048 chunks, 8 per thread)
    for (int c = tid; c < 2048; c += 256) {
        int lrow = c >> 4, coff = (c & 15) << 3;
        int grow = bm + lrow;
        if (grow < M) {
            if (MODE == 0) {
                int gcol = bn + coff;
                int s = gcol >> 5, o = gcol & 31;  // blocked [8][M][32]
                *(u16x8*)(Cout + ((size_t)s * M + (size_t)grow) * 32 + o) =
                    *(const u16x8*)&smem[lrow * CLD + coff];
            } else {
                *(u16x8*)(Cout + (size_t)grow * HID + bn + coff) =
                    *(const u16x8*)&smem[lrow * CLD + coff];
            }
        }
    }
}
#undef CLD

// Feature-slice-blocked aggregation v4: 16-deep gather batching + batched masked tail
// + LPT chunk reversal. 8 lanes/node x 8 B, desc-driven, swizzle-broadcast col.
// In: Hb blocked [S][NN][32] bf16 (slice table 3.2 MB, L2-resident via slice = bid&(S-1)
//     XCD pinning + segment-local degree sort).
// MLP: 16 gathers in flight per wave (vs 8); NO serial scalar tail -- remainder 1..7
// issues its gathers as one predicated batch. Chunk order reversed so high-degree
// blocks (perm is ascending-degree) dispatch FIRST (LPT -> no slow-block tail).
template <int S>
__global__ __launch_bounds__(256) void agg_slice_kernel(
        const unsigned short* __restrict__ Hb, const u32x4* __restrict__ desc,
        const int* __restrict__ col8,
        unsigned short* __restrict__ Out, int n, int nchunk) {
    constexpr int LOGS = (S == 8) ? 3 : 2;
    int bid = blockIdx.x;
    int s = bid & (S - 1);
    int chunk = nchunk - 1 - (bid >> LOGS);  // reversed: high-degree chunks first
    int idx = chunk * 32 + (threadIdx.x >> 3);
    if (idx >= n) return;
    int lane8 = threadIdx.x & 7;
    u32x4 d = desc[idx];
    int node8 = (int)d.x;
    int e = (int)d.y, eend = (int)d.z;
    float dv = __uint_as_float(d.w);
    const u32x2* Hv = (const u32x2*)Hb + (size_t)s * NN * 8;
    u32x2 p = Hv[node8 + lane8];  // self loop
    f32x2 a01 = {bflo(p.x), bfhi(p.x)};
    f32x2 a23 = {bflo(p.y), bfhi(p.y)};

    // 16-deep batches: 2 col vectors, 16 gathers in flight before any adds
    for (; e + 16 <= eend; e += 16) {
        int cv0 = col8[e + lane8];
        int cv1 = col8[e + 8 + lane8];
        u32x2 m[16];
#define G0(J) m[J] = Hv[bswz<J>(cv0) + lane8];
#define G1(J) m[8 + J] = Hv[bswz<J>(cv1) + lane8];
        G0(0) G0(1) G0(2) G0(3) G0(4) G0(5) G0(6) G0(7)
        G1(0) G1(1) G1(2) G1(3) G1(4) G1(5) G1(6) G1(7)
#undef G0
#undef G1
        #pragma unroll
        for (int j = 0; j < 16; ++j) {
            f32x2 lo = {bflo(m[j].x), bfhi(m[j].x)};
            f32x2 hi = {bflo(m[j].y), bfhi(m[j].y)};
            a01 = pkadd(a01, lo);
            a23 = pkadd(a23, hi);
        }
    }
    // one 8-deep batch
    if (e + 8 <= eend) {
        int cv0 = col8[e + lane8];
        u32x2 m[8];
#define G0(J) m[J] = Hv[bswz<J>(cv0) + lane8];
        G0(0) G0(1) G0(2) G0(3) G0(4) G0(5) G0(6) G0(7)
#undef G0
        #pragma unroll
        for (int j = 0; j < 8; ++j) {
            f32x2 lo = {bflo(m[j].x), bfhi(m[j].x)};
            f32x2 hi = {bflo(m[j].y), bfhi(m[j].y)};
            a01 = pkadd(a01, lo);
            a23 = pkadd(a23, hi);
        }
        e += 8;
    }
    // masked tail (1..7 edges): batched predicated gathers, no serial chain, no waste
    int t = eend - e;
    if (t > 0) {
        int il = e + lane8; if (il >= eend) il = eend - 1;  // clamp lanes >= t
        int cv0 = col8[il];
        u32x2 m[7];
#define GT(J) if (J < t) m[J] = Hv[bswz<J>(cv0) + lane8];
        GT(0) GT(1) GT(2) GT(3) GT(4) GT(5) GT(6)
#undef GT
#define AT(J) if (J < t) { f32x2 lo = {bflo(m[J].x), bfhi(m[J].x)}; \
                           f32x2 hi = {bflo(m[J].y), bfhi(m[J].y)}; \
                           a01 = pkadd(a01, lo); a23 = pkadd(a23, hi); }
        AT(0) AT(1) AT(2) AT(3) AT(4) AT(5) AT(6)
#undef AT
    }
    int node = node8 >> 3;
    u32x2 o;
    o.x = (unsigned int)f2bf(dv * a01.x) | ((unsigned int)f2bf(dv * a01.y) << 16);
    o.y = (unsigned int)f2bf(dv * a23.x) | ((unsigned int)f2bf(dv * a23.y) << 16);
    __builtin_nontemporal_store(o, (u32x2*)Out + (size_t)node * (S * 8) + s * 8 + lane8);
}

// one block per graph: mean-pool (bf16 Hf) + concat + FC1(relu) + FC2
__global__ __launch_bounds__(256) void pool_mlp_kernel(
        const unsigned short* __restrict__ H, const int* __restrict__ goff,
        const float* __restrict__ mol, const float* __restrict__ rings,
        const float* __restrict__ fcW1, const float* __restrict__ fcb1,
        const float* __restrict__ fcW2, const float* __restrict__ fcb2,
        float* __restrict__ out) {
    __shared__ float s_hg[258];
    __shared__ float s_t[196];
    int g = blockIdx.x, tid = threadIdx.x;
    int beg = goff[g], end = goff[g + 1];
    float acc = 0.f;
    for (int i = beg; i < end; ++i) acc += bf2f(H[(size_t)i * HID + tid]);
    s_hg[tid] = acc / fmaxf((float)(end - beg), 1.0f);
    if (tid == 0) { s_hg[256] = mol[g]; s_hg[257] = rings[g]; }
    __syncthreads();
    if (tid < 196) {
        float a = fcb1[tid];
        for (int k = 0; k < 258; ++k) a = fmaf(s_hg[k], fcW1[k * 196 + tid], a);
        s_t[tid] = fmaxf(a, 0.f);
    }
    __syncthreads();
    if (tid < 16) {
        float a = fcb2[tid];
        for (int k = 0; k < 196; ++k) a = fmaf(s_t[k], fcW2[k * 16 + tid], a);
        out[g * 16 + tid] = a;
    }
}

extern "C" void kernel_launch(void* const* d_in, const int* in_sizes, int n_in,
                              void* d_out, int out_size, void* d_ws, size_t ws_size,
                              hipStream_t stream) {
    const float* x     = (const float*)d_in[0];
    const int*   ei    = (const int*)d_in[1];
    const int*   batch = (const int*)d_in[2];
    const float* mol   = (const float*)d_in[3];
    const float* rings = (const float*)d_in[4];
    const float* W1 = (const float*)d_in[5];
    const float* b1 = (const float*)d_in[6];
    const float* W2 = (const float*)d_in[7];
    const float* b2 = (const float*)d_in[8];
    const float* W3 = (const float*)d_in[9];
    const float* b3 = (const float*)d_in[10];
    const float* fcW1 = (const float*)d_in[11];
    const float* fcb1 = (const float*)d_in[12];
    const float* fcW2 = (const float*)d_in[13];
    const float* fcb2 = (const float*)d_in[14];
    float* out = (float*)d_out;
    const int* src = ei;
    const int* dst = ei + NE;

    char* w = (char*)d_ws;
    auto alloc = [&](size_t bytes) {
        char* p = w;
        w += (bytes + 255) & ~(size_t)255;
        return p;
    };
    int*   gbuk    = (int*)alloc((size_t)NBUK * 4);
    int*   bukoff  = (int*)alloc((size_t)(NBUK + 1) * 4);
    int*   bukcur  = (int*)alloc((size_t)NBUK * 4);
    int*   row_ptr = (int*)alloc((size_t)(NN + 1) * 4);
    int*   goff    = (int*)alloc((size_t)(NG + 1) * 4);
    float* dis     = (float*)alloc((size_t)NN * 4);
    u32x4* desc    = (u32x4*)alloc((size_t)NN * 16);
    unsigned int* pairs = (unsigned int*)alloc((size_t)NE * 4);
    int*   col8    = (int*)alloc((size_t)NE * 4);
    unsigned short* Xs  = (unsigned short*)alloc((size_t)NN * FIN * 2);  // blocked [4][NN][32]
    unsigned short* Xa  = (unsigned short*)alloc((size_t)NN * FIN * 2);  // row-major
    unsigned short* Hs  = (unsigned short*)alloc((size_t)NN * HID * 2);  // blocked [8][NN][32]
    unsigned short* Ga  = (unsigned short*)alloc((size_t)NN * HID * 2);  // row-major
    unsigned short* Hf  = (unsigned short*)alloc((size_t)NN * HID * 2);  // row-major
    unsigned short* W1t = (unsigned short*)alloc((size_t)FIN * HID * 2);
    unsigned short* W2t = (unsigned short*)alloc((size_t)HID * HID * 2);
    unsigned short* W3t = (unsigned short*)alloc((size_t)HID * HID * 2);

    hipMemsetAsync(gbuk, 0, (size_t)NBUK * 4, stream);
    int eb = cdiv(NE, 2048);  // 391
    hist_bucket_kernel<<<eb, 256, 0, stream>>>(dst, gbuk);
    goff_kernel<<<cdiv(NN, 256), 256, 0, stream>>>(batch, goff);
    buk_scan_kernel<<<1, 256, 0, stream>>>(gbuk, bukoff, bukcur);
    scatter_kernel<<<eb, 256, 0, stream>>>(src, dst, bukcur, pairs);
    local_csr_kernel<<<NBUK, 256, 0, stream>>>(pairs, bukoff, row_ptr, col8, dis);
    segperm_kernel<<<cdiv(NN, SEGSZ), 256, 0, stream>>>(row_ptr, dis, desc);

    cast_scale_kernel<<<cdiv(NN * FIN / 4, 256), 256, 0, stream>>>(x, dis, Xs, NN * FIN / 4);
    tcast_all_kernel<<<cdiv((FIN + HID + HID) * 256, 256), 256, 0, stream>>>(W1, W2, W3, W1t, W2t, W3t);

    dim3 ggrid(cdiv(NN, 128), 2);
    int achunks = cdiv(NN, 32);  // 1563
    // all layers: aggregate-then-transform (aggregation commutes with @W)
    agg_slice_kernel<4><<<4 * achunks, 256, 0, stream>>>(Xs, desc, col8, Xa, NN, achunks);
    gemm128_kernel<0><<<ggrid, 256, 0, stream>>>(Xa, W1t, dis, b1, Hs, NN, FIN);  // Hs1 blocked
    agg_slice_kernel<8><<<8 * achunks, 256, 0, stream>>>(Hs, desc, col8, Ga, NN, achunks);
    gemm128_kernel<0><<<ggrid, 256, 0, stream>>>(Ga, W2t, dis, b2, Hs, NN, HID);  // Hs2 blocked
    agg_slice_kernel<8><<<8 * achunks, 256, 0, stream>>>(Hs, desc, col8, Ga, NN, achunks);
    gemm128_kernel<1><<<ggrid, 256, 0, stream>>>(Ga, W3t, dis, b3, Hf, NN, HID);  // Hf row-major
    pool_mlp_kernel<<<NG, 256, 0, stream>>>(Hf, goff, mol, rings, fcW1, fcb1, fcW2, fcb2, out);
}

// Round 9
// 351.345 us; speedup vs baseline: 1.5312x; 1.0405x over previous
//
#include <hip/hip_runtime.h>

#define NN 50000
#define NE 800000
#define NG 512
#define FIN 128
#define HID 256
#define NBUK 196   // buckets of 256 node ids: ceil(50000/256)
#define SEGSZ 2048 // segment size for the locality-preserving degree sort

typedef short short8 __attribute__((ext_vector_type(8)));
typedef float f32x4 __attribute__((ext_vector_type(4)));
typedef float f32x2 __attribute__((ext_vector_type(2)));
typedef unsigned short u16x8 __attribute__((ext_vector_type(8)));
typedef unsigned int u32x2 __attribute__((ext_vector_type(2)));
typedef unsigned int u32x4 __attribute__((ext_vector_type(4)));

static inline int cdiv(int a, int b) { return (a + b - 1) / b; }

static __device__ inline unsigned short f2bf(float f) {
    unsigned int u = __float_as_uint(f);
    unsigned int r = (u + 0x7FFF + ((u >> 16) & 1)) >> 16;  // RNE
    return (unsigned short)r;
}
static __device__ inline float bf2f(unsigned short h) {
    return __uint_as_float(((unsigned int)h) << 16);
}
static __device__ inline float bflo(unsigned int p) { return __uint_as_float(p << 16); }
static __device__ inline float bfhi(unsigned int p) { return __uint_as_float(p & 0xFFFF0000u); }

// packed fp32 add (gfx90a+): 1 instr for 2 lane-local f32 adds
static __device__ __forceinline__ f32x2 pkadd(f32x2 a, f32x2 b) {
    f32x2 r;
    asm("v_pk_add_f32 %0, %1, %2" : "=v"(r) : "v"(a), "v"(b));
    return r;
}

// ds_swizzle broadcast within each 8-lane group: all lanes get lane (group*8+J)'s value.
// BitMode offset: xor=0, or=J, and=0x18 (keep group bits, force low3 = J).
template <int J>
static __device__ __forceinline__ int bswz(int v) {
    return __builtin_amdgcn_ds_swizzle(v, (J << 5) | 0x18);
}

typedef __attribute__((address_space(1))) unsigned int gu32;
typedef __attribute__((address_space(3))) unsigned int lu32;
static __device__ __forceinline__ void gload16(const unsigned short* g, unsigned short* l) {
    __builtin_amdgcn_global_load_lds((const gu32*)(const void*)g, (lu32*)(void*)l, 16, 0, 0);
}

// ---- CSR build, bucket-sort style (no per-edge global atomics) ----

// coarse 196-bucket histogram of dst, LDS-privatized
__global__ __launch_bounds__(256) void hist_bucket_kernel(const int* __restrict__ dst,
                                                          int* __restrict__ gbuk) {
    __shared__ int lh[NBUK];
    int tid = threadIdx.x;
    for (int j = tid; j < NBUK; j += 256) lh[j] = 0;
    __syncthreads();
    int base = blockIdx.x * 2048;
    #pragma unroll
    for (int k = 0; k < 8; ++k) {
        int i = base + k * 256 + tid;
        if (i < NE) atomicAdd(&lh[dst[i] >> 8], 1);
    }
    __syncthreads();
    for (int j = tid; j < NBUK; j += 256) if (lh[j]) atomicAdd(&gbuk[j], lh[j]);
}

// batch is sorted: goff by boundary detection, no atomics
__global__ void goff_kernel(const int* __restrict__ batch, int* __restrict__ goff) {
    int i = blockIdx.x * 256 + threadIdx.x;
    if (i >= NN) return;
    int b = batch[i];
    int pb = (i == 0) ? -1 : batch[i - 1];
    for (int g = pb + 1; g <= b; ++g) goff[g] = i;
    if (i == NN - 1) for (int g = b + 1; g <= NG; ++g) goff[g] = NN;
}

// single-block exclusive scan of gbuk[196] -> bukoff[197], plus cursor copy
__global__ void buk_scan_kernel(const int* __restrict__ gbuk, int* __restrict__ bukoff,
                                int* __restrict__ bukcur) {
    __shared__ int ws[4];
    int tid = threadIdx.x, lane = tid & 63, wid = tid >> 6;
    int v = (tid < NBUK) ? gbuk[tid] : 0;
    int incl = v;
    #pragma unroll
    for (int off = 1; off < 64; off <<= 1) {
        int u = __shfl_up(incl, off, 64);
        if (lane >= off) incl += u;
    }
    if (lane == 63) ws[wid] = incl;
    __syncthreads();
    int woff = 0;
    for (int w = 0; w < wid; ++w) woff += ws[w];
    int ex = woff + incl - v;
    if (tid < NBUK) { bukoff[tid] = ex; bukcur[tid] = ex; }
    if (tid == NBUK - 1) bukoff[NBUK] = ex + v;
}

// scatter edges into bucket-contiguous pairs[]; one global atomic per block per bucket
__global__ __launch_bounds__(256) void scatter_kernel(const int* __restrict__ src,
                                                      const int* __restrict__ dst,
                                                      int* __restrict__ bukcur,
                                                      unsigned int* __restrict__ pairs) {
    __shared__ int lh[NBUK];
    __shared__ int lbase[NBUK];
    int tid = threadIdx.x;
    for (int j = tid; j < NBUK; j += 256) lh[j] = 0;
    __syncthreads();
    int base = blockIdx.x * 2048;
    int d[8], s[8];
    #pragma unroll
    for (int k = 0; k < 8; ++k) {
        int i = base + k * 256 + tid;
        if (i < NE) {
            d[k] = dst[i]; s[k] = src[i];
            atomicAdd(&lh[d[k] >> 8], 1);
        } else d[k] = -1;
    }
    __syncthreads();
    for (int j = tid; j < NBUK; j += 256) lbase[j] = lh[j] ? atomicAdd(&bukcur[j], lh[j]) : 0;
    __syncthreads();
    for (int j = tid; j < NBUK; j += 256) lh[j] = 0;
    __syncthreads();
    #pragma unroll
    for (int k = 0; k < 8; ++k) {
        if (d[k] >= 0) {
            int b = d[k] >> 8;
            int loc = atomicAdd(&lh[b], 1);
            pairs[lbase[b] + loc] = ((unsigned int)s[k] << 16) | (unsigned int)(d[k] & 255);
        }
    }
}

// per-bucket fine CSR: row_ptr, col8 (pre-shifted src: col<<3 = uint2-unit row offset),
// dis (one block per bucket)
__global__ __launch_bounds__(256) void local_csr_kernel(const unsigned int* __restrict__ pairs,
                                                        const int* __restrict__ bukoff,
                                                        int* __restrict__ row_ptr,
                                                        int* __restrict__ col8,
                                                        float* __restrict__ dis) {
    __shared__ int fcnt[256];
    __shared__ int foff[256];
    __shared__ int fws[4];
    int b = blockIdx.x, tid = threadIdx.x;
    int beg = bukoff[b], end = bukoff[b + 1];
    fcnt[tid] = 0;
    __syncthreads();
    for (int i = beg + tid; i < end; i += 256) atomicAdd(&fcnt[pairs[i] & 255], 1);
    __syncthreads();
    int lane = tid & 63, wid = tid >> 6;
    int v = fcnt[tid], incl = v;
    #pragma unroll
    for (int off = 1; off < 64; off <<= 1) {
        int u = __shfl_up(incl, off, 64);
        if (lane >= off) incl += u;
    }
    if (lane == 63) fws[wid] = incl;
    __syncthreads();
    int woff = 0;
    for (int w = 0; w < wid; ++w) woff += fws[w];
    int ex = woff + incl - v;  // exclusive fine offset
    foff[tid] = ex;
    int gid = b * 256 + tid;
    if (gid < NN) {
        row_ptr[gid] = beg + ex;
        dis[gid] = rsqrtf((float)v + 1.0f);
    }
    if (b == 0 && tid == 0) row_ptr[NN] = NE;
    __syncthreads();
    // scatter src into col8 using foff as LDS cursors
    for (int i = beg + tid; i < end; i += 256) {
        unsigned int p = pairs[i];
        int loc = atomicAdd(&foff[p & 255], 1);
        col8[beg + loc] = (int)(p >> 16) << 3;
    }
}

// SEGMENT-LOCAL degree sort -> work DESCRIPTORS. One block per 2048-node segment:
// LDS histogram + scan + LDS-cursor scatter, zero global atomics. Groups equal-degree
// nodes (wave-uniform trip counts) while keeping each agg block inside a 2048-node
// window (slice table stays L2-resident). desc[idx] = {node*8, e_beg, e_end, dis bits}:
// one 16B load replaces the perm->row_ptr->dis dependent chain in every agg pass.
__global__ __launch_bounds__(256) void segperm_kernel(const int* __restrict__ row_ptr,
                                                      const float* __restrict__ dis,
                                                      u32x4* __restrict__ desc) {
    __shared__ int hist[256];
    __shared__ int ws[4];
    int tid = threadIdx.x;
    int base = blockIdx.x * SEGSZ;
    int segN = NN - base; if (segN > SEGSZ) segN = SEGSZ;
    hist[tid] = 0;
    __syncthreads();
    int dbin[8], rb[8], dreal[8];
    #pragma unroll
    for (int k = 0; k < 8; ++k) {
        int j = k * 256 + tid;
        if (j < segN) {
            rb[k] = row_ptr[base + j];
            dreal[k] = row_ptr[base + j + 1] - rb[k];
            int d = dreal[k] > 255 ? 255 : dreal[k];
            dbin[k] = d;
            atomicAdd(&hist[d], 1);
        } else dbin[k] = -1;
    }
    __syncthreads();
    int lane = tid & 63, wid = tid >> 6;
    int v = hist[tid], incl = v;
    #pragma unroll
    for (int off = 1; off < 64; off <<= 1) {
        int u = __shfl_up(incl, off, 64);
        if (lane >= off) incl += u;
    }
    if (lane == 63) ws[wid] = incl;
    __syncthreads();
    int woff = 0;
    for (int w = 0; w < wid; ++w) woff += ws[w];
    __syncthreads();
    hist[tid] = woff + incl - v;  // exclusive offset becomes bin cursor
    __syncthreads();
    #pragma unroll
    for (int k = 0; k < 8; ++k) {
        if (dbin[k] >= 0) {
            int rank = atomicAdd(&hist[dbin[k]], 1);
            int node = base + k * 256 + tid;
            u32x4 dd;
            dd.x = (unsigned int)(node * 8);
            dd.y = (unsigned int)rb[k];
            dd.z = (unsigned int)(rb[k] + dreal[k]);
            dd.w = __float_as_uint(dis[node]);
            desc[base + rank] = dd;
        }
    }
}

// Xb[s][i][f'] = bf16(dis[i] * x[i][f])  -- blocked layout, 4 slices of 32 feats
__global__ void cast_scale_kernel(const float* __restrict__ x, const float* __restrict__ dis,
                                  unsigned short* __restrict__ Xb, int n4) {
    int i = blockIdx.x * 256 + threadIdx.x;  // float4 index over [NN][128]
    if (i < n4) {
        int node = i >> 5;   // 32 float4 per row
        int f4 = i & 31;     // float4 index within row
        int s = f4 >> 3;     // slice = feat>>5
        int o = f4 & 7;      // float4 within the 32-feat slice
        float dv = dis[node];
        float4 v = ((const float4*)x)[i];
        ushort4 w;
        w.x = f2bf(dv * v.x); w.y = f2bf(dv * v.y); w.z = f2bf(dv * v.z); w.w = f2bf(dv * v.w);
        ((ushort4*)Xb)[((size_t)s * NN + (size_t)node) * 8 + o] = w;
    }
}

// all three weights transposed+cast in one dispatch: W [K,256] fp32 -> Wt [256,K] bf16
__global__ void tcast_all_kernel(const float* __restrict__ W1, const float* __restrict__ W2,
                                 const float* __restrict__ W3,
                                 unsigned short* __restrict__ W1t, unsigned short* __restrict__ W2t,
                                 unsigned short* __restrict__ W3t) {
    int idx = blockIdx.x * 256 + threadIdx.x;
    if (idx < FIN * 256) {
        int n = idx / FIN, k = idx - n * FIN;
        W1t[idx] = f2bf(W1[(size_t)k * 256 + n]);
    } else if (idx < FIN * 256 + HID * 256) {
        int t = idx - FIN * 256;
        int n = t / HID, k = t - n * HID;
        W2t[t] = f2bf(W2[(size_t)k * 256 + n]);
    } else {
        int t = idx - FIN * 256 - HID * 256;
        int n = t / HID, k = t - n * HID;
        W3t[t] = f2bf(W3[(size_t)k * 256 + n]);
    }
}

// 128x128 GEMM, BK=32, global_load_lds staging, LDS-bounce coalesced epilogue.
// A:[M,K] bf16 row-major, Bt:[256,K] bf16.
// MODE 0: Hs = bf16(dis[row]*relu(acc + bias[col])) -> BLOCKED [8][M][32] (feeds slice-agg)
// MODE 1: Hf = bf16(relu(acc + bias[col]))          -> row-major [M][256] (feeds pooling)
#define CLD 136   // C-tile LDS row stride in shorts (mult of 8 -> 16B-aligned rows)
template <int MODE>
__global__ __launch_bounds__(256) void gemm128_kernel(
        const unsigned short* __restrict__ A, const unsigned short* __restrict__ Bt,
        const float* __restrict__ dis, const float* __restrict__ bias,
        unsigned short* __restrict__ Cout, int M, int K) {
    __shared__ unsigned short smem[128 * CLD];  // K-loop: As=smem[0:4096], Bs=smem[4096:8192]
    unsigned short* As = smem;
    unsigned short* Bs = smem + 4096;
    const int tid = threadIdx.x;
    const int bm = blockIdx.x * 128, bn = blockIdx.y * 128;
    const int wave = tid >> 6, lane = tid & 63;
    const int l16 = lane & 15, quad = lane >> 4;
    const int wm = (wave & 1) * 64, wn = (wave >> 1) * 64;

    int srow0 = tid >> 2, skc = (tid & 3) * 8;
    int srow1 = (256 + tid) >> 2;
    int ar0 = bm + srow0; if (ar0 > M - 1) ar0 = M - 1;
    int ar1 = bm + srow1; if (ar1 > M - 1) ar1 = M - 1;

    f32x4 acc[4][4];
    #pragma unroll
    for (int i = 0; i < 4; ++i)
        #pragma unroll
        for (int j = 0; j < 4; ++j) acc[i][j] = (f32x4){0.f, 0.f, 0.f, 0.f};

    for (int k0 = 0; k0 < K; k0 += 32) {
        gload16(A + (size_t)ar0 * K + k0 + skc, &As[(size_t)tid * 8]);
        gload16(A + (size_t)ar1 * K + k0 + skc, &As[(size_t)(256 + tid) * 8]);
        gload16(Bt + (size_t)(bn + srow0) * K + k0 + skc, &Bs[(size_t)tid * 8]);
        gload16(Bt + (size_t)(bn + srow1) * K + k0 + skc, &Bs[(size_t)(256 + tid) * 8]);
        __syncthreads();
        short8 af[4], bf[4];
        #pragma unroll
        for (int mt = 0; mt < 4; ++mt) af[mt] = *(const short8*)&As[(wm + mt * 16 + l16) * 32 + quad * 8];
        #pragma unroll
        for (int nt = 0; nt < 4; ++nt) bf[nt] = *(const short8*)&Bs[(wn + nt * 16 + l16) * 32 + quad * 8];
        #pragma unroll
        for (int mt = 0; mt < 4; ++mt)
            #pragma unroll
            for (int nt = 0; nt < 4; ++nt)
                acc[mt][nt] = __builtin_amdgcn_mfma_f32_16x16x32_bf16(af[mt], bf[nt], acc[mt][nt], 0, 0, 0);
        __syncthreads();
    }
    // phase 1: acc -> LDS tile (bf16), bias/relu/dis applied.  C/D: col=l16+16nt+wn, row=quad*4+r+16mt+wm
    float bv[4];
    #pragma unroll
    for (int nt = 0; nt < 4; ++nt) bv[nt] = bias[bn + wn + nt * 16 + l16];
    #pragma unroll
    for (int mt = 0; mt < 4; ++mt) {
        #pragma unroll
        for (int r = 0; r < 4; ++r) {
            int lrow = wm + mt * 16 + quad * 4 + r;
            int grow = bm + lrow; if (grow > M - 1) grow = M - 1;
            float dv = (MODE == 0) ? dis[grow] : 1.0f;
            #pragma unroll
            for (int nt = 0; nt < 4; ++nt) {
                float v = fmaxf(acc[mt][nt][r] + bv[nt], 0.f);
                if (MODE == 0) v *= dv;
                smem[lrow * CLD + wn + nt * 16 + l16] = f2bf(v);
            }
        }
    }
    __syncthreads();
    // phase 2: LDS -> global, 16B coalesced chunks (2048 chunks, 8 per thread)
    for (int c = tid; c < 2048; c += 256) {
        int lrow = c >> 4, coff = (c & 15) << 3;
        int grow = bm + lrow;
        if (grow < M) {
            if (MODE == 0) {
                int gcol = bn + coff;
                int s = gcol >> 5, o = gcol & 31;  // blocked [8][M][32]
                *(u16x8*)(Cout + ((size_t)s * M + (size_t)grow) * 32 + o) =
                    *(const u16x8*)&smem[lrow * CLD + coff];
            } else {
                *(u16x8*)(Cout + (size_t)grow * HID + bn + coff) =
                    *(const u16x8*)&smem[lrow * CLD + coff];
            }
        }
    }
}
#undef CLD

// Feature-slice-blocked aggregation v4: 16-deep gather batching + batched masked tail
// + LPT chunk reversal. 8 lanes/node x 8 B, desc-driven, swizzle-broadcast col.
// In: Hb blocked [S][NN][32] bf16 (slice table 3.2 MB, L2-resident via slice = bid&(S-1)
//     XCD pinning + segment-local degree sort).
// MLP: 16 gathers in flight per wave (vs 8); NO serial scalar tail -- remainder 1..7
// issues its gathers as one predicated batch. Chunk order reversed so high-degree
// blocks (perm is ascending-degree) dispatch FIRST (LPT -> no slow-block tail).
template <int S>
__global__ __launch_bounds__(256) void agg_slice_kernel(
        const unsigned short* __restrict__ Hb, const u32x4* __restrict__ desc,
        const int* __restrict__ col8,
        unsigned short* __restrict__ Out, int n, int nchunk) {
    constexpr int LOGS = (S == 8) ? 3 : 2;
    int bid = blockIdx.x;
    int s = bid & (S - 1);
    int chunk = nchunk - 1 - (bid >> LOGS);  // reversed: high-degree chunks first
    int idx = chunk * 32 + (threadIdx.x >> 3);
    if (idx >= n) return;
    int lane8 = threadIdx.x & 7;
    u32x4 d = desc[idx];
    int node8 = (int)d.x;
    int e = (int)d.y, eend = (int)d.z;
    float dv = __uint_as_float(d.w);
    const u32x2* Hv = (const u32x2*)Hb + (size_t)s * NN * 8;
    u32x2 p = Hv[node8 + lane8];  // self loop
    f32x2 a01 = {bflo(p.x), bfhi(p.x)};
    f32x2 a23 = {bflo(p.y), bfhi(p.y)};

    // 16-deep batches: 2 col vectors, 16 gathers in flight before any adds
    for (; e + 16 <= eend; e += 16) {
        int cv0 = col8[e + lane8];
        int cv1 = col8[e + 8 + lane8];
        u32x2 m[16];
#define G0(J) m[J] = Hv[bswz<J>(cv0) + lane8];
#define G1(J) m[8 + J] = Hv[bswz<J>(cv1) + lane8];
        G0(0) G0(1) G0(2) G0(3) G0(4) G0(5) G0(6) G0(7)
        G1(0) G1(1) G1(2) G1(3) G1(4) G1(5) G1(6) G1(7)
#undef G0
#undef G1
        #pragma unroll
        for (int j = 0; j < 16; ++j) {
            f32x2 lo = {bflo(m[j].x), bfhi(m[j].x)};
            f32x2 hi = {bflo(m[j].y), bfhi(m[j].y)};
            a01 = pkadd(a01, lo);
            a23 = pkadd(a23, hi);
        }
    }
    // one 8-deep batch
    if (e + 8 <= eend) {
        int cv0 = col8[e + lane8];
        u32x2 m[8];
#define G0(J) m[J] = Hv[bswz<J>(cv0) + lane8];
        G0(0) G0(1) G0(2) G0(3) G0(4) G0(5) G0(6) G0(7)
#undef G0
        #pragma unroll
        for (int j = 0; j < 8; ++j) {
            f32x2 lo = {bflo(m[j].x), bfhi(m[j].x)};
            f32x2 hi = {bflo(m[j].y), bfhi(m[j].y)};
            a01 = pkadd(a01, lo);
            a23 = pkadd(a23, hi);
        }
        e += 8;
    }
    // masked tail (1..7 edges): batched predicated gathers, no serial chain, no waste
    int t = eend - e;
    if (t > 0) {
        int il = e + lane8; if (il >= eend) il = eend - 1;  // clamp lanes >= t
        int cv0 = col8[il];
        u32x2 m[7];
#define GT(J) if (J < t) m[J] = Hv[bswz<J>(cv0) + lane8];
        GT(0) GT(1) GT(2) GT(3) GT(4) GT(5) GT(6)
#undef GT
#define AT(J) if (J < t) { f32x2 lo = {bflo(m[J].x), bfhi(m[J].x)}; \
                           f32x2 hi = {bflo(m[J].y), bfhi(m[J].y)}; \
                           a01 = pkadd(a01, lo); a23 = pkadd(a23, hi); }
        AT(0) AT(1) AT(2) AT(3) AT(4) AT(5) AT(6)
#undef AT
    }
    int node = node8 >> 3;
    u32x2 o;
    o.x = (unsigned int)f2bf(dv * a01.x) | ((unsigned int)f2bf(dv * a01.y) << 16);
    o.y = (unsigned int)f2bf(dv * a23.x) | ((unsigned int)f2bf(dv * a23.y) << 16);
    __builtin_nontemporal_store(o, (u32x2*)Out + (size_t)node * (S * 8) + s * 8 + lane8);
}

// Pooling stage 1: 4 blocks per graph, threads [node_par=4][feat=64 x f32x4].
// 4-deep batched row loads (vs old serial load->waitcnt->add chain that cost ~24 us).
// Partials to part[2048][256] fp32 -- no atomics, summed in mlp_kernel.
__global__ __launch_bounds__(256) void pool_part_kernel(
        const unsigned short* __restrict__ H, const int* __restrict__ goff,
        float* __restrict__ part) {
    __shared__ float red[3][64][4];
    int bid = blockIdx.x;
    int g = bid >> 2, q = bid & 3;
    int beg = goff[g], end = goff[g + 1];
    int len = end - beg;
    int qb = beg + ((len * q) >> 2), qe = beg + ((len * (q + 1)) >> 2);
    int tp = threadIdx.x >> 6, tf = threadIdx.x & 63;
    float4 acc = make_float4(0.f, 0.f, 0.f, 0.f);
    int i = qb + tp;
    for (; i + 12 < qe; i += 16) {  // 4 rows/thread in flight (stride 4 = node_par)
        ushort4 v0 = *(const ushort4*)&H[(size_t)(i     ) * HID + tf * 4];
        ushort4 v1 = *(const ushort4*)&H[(size_t)(i +  4) * HID + tf * 4];
        ushort4 v2 = *(const ushort4*)&H[(size_t)(i +  8) * HID + tf * 4];
        ushort4 v3 = *(const ushort4*)&H[(size_t)(i + 12) * HID + tf * 4];
        acc.x += bf2f(v0.x) + bf2f(v1.x) + bf2f(v2.x) + bf2f(v3.x);
        acc.y += bf2f(v0.y) + bf2f(v1.y) + bf2f(v2.y) + bf2f(v3.y);
        acc.z += bf2f(v0.z) + bf2f(v1.z) + bf2f(v2.z) + bf2f(v3.z);
        acc.w += bf2f(v0.w) + bf2f(v1.w) + bf2f(v2.w) + bf2f(v3.w);
    }
    for (; i < qe; i += 4) {
        ushort4 v = *(const ushort4*)&H[(size_t)i * HID + tf * 4];
        acc.x += bf2f(v.x); acc.y += bf2f(v.y); acc.z += bf2f(v.z); acc.w += bf2f(v.w);
    }
    if (tp > 0) {
        red[tp - 1][tf][0] = acc.x; red[tp - 1][tf][1] = acc.y;
        red[tp - 1][tf][2] = acc.z; red[tp - 1][tf][3] = acc.w;
    }
    __syncthreads();
    if (tp == 0) {
        acc.x += red[0][tf][0] + red[1][tf][0] + red[2][tf][0];
        acc.y += red[0][tf][1] + red[1][tf][1] + red[2][tf][1];
        acc.z += red[0][tf][2] + red[1][tf][2] + red[2][tf][2];
        acc.w += red[0][tf][3] + red[1][tf][3] + red[2][tf][3];
        ((float4*)part)[(size_t)bid * 64 + tf] = acc;
    }
}

// Pooling stage 2 + MLP: sum 4 partials, mean, concat, FC1 (8-way batched loads),
// FC2 as 16x16 partial dots + LDS reduce (vs 16 threads x 196 serial iters).
__global__ __launch_bounds__(256) void mlp_kernel(
        const float* __restrict__ part, const int* __restrict__ goff,
        const float* __restrict__ mol, const float* __restrict__ rings,
        const float* __restrict__ fcW1, const float* __restrict__ fcb1,
        const float* __restrict__ fcW2, const float* __restrict__ fcb2,
        float* __restrict__ out) {
    __shared__ float s_hg[258];
    __shared__ float s_t[196];
    __shared__ float s_p[16][16];
    int g = blockIdx.x, tid = threadIdx.x;
    int len = goff[g + 1] - goff[g];
    const float* pg = part + (size_t)g * 1024;
    float v = pg[tid] + pg[256 + tid] + pg[512 + tid] + pg[768 + tid];
    s_hg[tid] = v / fmaxf((float)len, 1.0f);
    if (tid == 0) { s_hg[256] = mol[g]; s_hg[257] = rings[g]; }
    __syncthreads();
    if (tid < 196) {
        float a = fcb1[tid];
        int k = 0;
        for (; k + 8 <= 258; k += 8) {  // 8 weight loads in flight
            float w0 = fcW1[(k + 0) * 196 + tid];
            float w1 = fcW1[(k + 1) * 196 + tid];
            float w2 = fcW1[(k + 2) * 196 + tid];
            float w3 = fcW1[(k + 3) * 196 + tid];
            float w4 = fcW1[(k + 4) * 196 + tid];
            float w5 = fcW1[(k + 5) * 196 + tid];
            float w6 = fcW1[(k + 6) * 196 + tid];
            float w7 = fcW1[(k + 7) * 196 + tid];
            a = fmaf(s_hg[k + 0], w0, a); a = fmaf(s_hg[k + 1], w1, a);
            a = fmaf(s_hg[k + 2], w2, a); a = fmaf(s_hg[k + 3], w3, a);
            a = fmaf(s_hg[k + 4], w4, a); a = fmaf(s_hg[k + 5], w5, a);
            a = fmaf(s_hg[k + 6], w6, a); a = fmaf(s_hg[k + 7], w7, a);
        }
        for (; k < 258; ++k) a = fmaf(s_hg[k], fcW1[k * 196 + tid], a);
        s_t[tid] = fmaxf(a, 0.f);
    }
    __syncthreads();
    {
        int o = tid & 15, kp = tid >> 4;
        float a = 0.f;
        for (int k = kp; k < 196; k += 16) a = fmaf(s_t[k], fcW2[k * 16 + o], a);
        s_p[kp][o] = a;
    }
    __syncthreads();
    if (tid < 16) {
        float a = fcb2[tid];
        #pragma unroll
        for (int kp = 0; kp < 16; ++kp) a += s_p[kp][tid];
        out[g * 16 + tid] = a;
    }
}

extern "C" void kernel_launch(void* const* d_in, const int* in_sizes, int n_in,
                              void* d_out, int out_size, void* d_ws, size_t ws_size,
                              hipStream_t stream) {
    const float* x     = (const float*)d_in[0];
    const int*   ei    = (const int*)d_in[1];
    const int*   batch = (const int*)d_in[2];
    const float* mol   = (const float*)d_in[3];
    const float* rings = (const float*)d_in[4];
    const float* W1 = (const float*)d_in[5];
    const float* b1 = (const float*)d_in[6];
    const float* W2 = (const float*)d_in[7];
    const float* b2 = (const float*)d_in[8];
    const float* W3 = (const float*)d_in[9];
    const float* b3 = (const float*)d_in[10];
    const float* fcW1 = (const float*)d_in[11];
    const float* fcb1 = (const float*)d_in[12];
    const float* fcW2 = (const float*)d_in[13];
    const float* fcb2 = (const float*)d_in[14];
    float* out = (float*)d_out;
    const int* src = ei;
    const int* dst = ei + NE;

    char* w = (char*)d_ws;
    auto alloc = [&](size_t bytes) {
        char* p = w;
        w += (bytes + 255) & ~(size_t)255;
        return p;
    };
    int*   gbuk    = (int*)alloc((size_t)NBUK * 4);
    int*   bukoff  = (int*)alloc((size_t)(NBUK + 1) * 4);
    int*   bukcur  = (int*)alloc((size_t)NBUK * 4);
    int*   row_ptr = (int*)alloc((size_t)(NN + 1) * 4);
    int*   goff    = (int*)alloc((size_t)(NG + 1) * 4);
    float* dis     = (float*)alloc((size_t)NN * 4);
    u32x4* desc    = (u32x4*)alloc((size_t)NN * 16);
    unsigned int* pairs = (unsigned int*)alloc((size_t)NE * 4);
    int*   col8    = (int*)alloc((size_t)NE * 4);
    float* part    = (float*)alloc((size_t)NG * 4 * 256 * 4);  // [2048][256] fp32 pool partials
    unsigned short* Xs  = (unsigned short*)alloc((size_t)NN * FIN * 2);  // blocked [4][NN][32]
    unsigned short* Xa  = (unsigned short*)alloc((size_t)NN * FIN * 2);  // row-major
    unsigned short* Hs  = (unsigned short*)alloc((size_t)NN * HID * 2);  // blocked [8][NN][32]
    unsigned short* Ga  = (unsigned short*)alloc((size_t)NN * HID * 2);  // row-major
    unsigned short* Hf  = (unsigned short*)alloc((size_t)NN * HID * 2);  // row-major
    unsigned short* W1t = (unsigned short*)alloc((size_t)FIN * HID * 2);
    unsigned short* W2t = (unsigned short*)alloc((size_t)HID * HID * 2);
    unsigned short* W3t = (unsigned short*)alloc((size_t)HID * HID * 2);

    hipMemsetAsync(gbuk, 0, (size_t)NBUK * 4, stream);
    int eb = cdiv(NE, 2048);  // 391
    hist_bucket_kernel<<<eb, 256, 0, stream>>>(dst, gbuk);
    goff_kernel<<<cdiv(NN, 256), 256, 0, stream>>>(batch, goff);
    buk_scan_kernel<<<1, 256, 0, stream>>>(gbuk, bukoff, bukcur);
    scatter_kernel<<<eb, 256, 0, stream>>>(src, dst, bukcur, pairs);
    local_csr_kernel<<<NBUK, 256, 0, stream>>>(pairs, bukoff, row_ptr, col8, dis);
    segperm_kernel<<<cdiv(NN, SEGSZ), 256, 0, stream>>>(row_ptr, dis, desc);

    cast_scale_kernel<<<cdiv(NN * FIN / 4, 256), 256, 0, stream>>>(x, dis, Xs, NN * FIN / 4);
    tcast_all_kernel<<<cdiv((FIN + HID + HID) * 256, 256), 256, 0, stream>>>(W1, W2, W3, W1t, W2t, W3t);

    dim3 ggrid(cdiv(NN, 128), 2);
    int achunks = cdiv(NN, 32);  // 1563
    // all layers: aggregate-then-transform (aggregation commutes with @W)
    agg_slice_kernel<4><<<4 * achunks, 256, 0, stream>>>(Xs, desc, col8, Xa, NN, achunks);
    gemm128_kernel<0><<<ggrid, 256, 0, stream>>>(Xa, W1t, dis, b1, Hs, NN, FIN);  // Hs1 blocked
    agg_slice_kernel<8><<<8 * achunks, 256, 0, stream>>>(Hs, desc, col8, Ga, NN, achunks);
    gemm128_kernel<0><<<ggrid, 256, 0, stream>>>(Ga, W2t, dis, b2, Hs, NN, HID);  // Hs2 blocked
    agg_slice_kernel<8><<<8 * achunks, 256, 0, stream>>>(Hs, desc, col8, Ga, NN, achunks);
    gemm128_kernel<1><<<ggrid, 256, 0, stream>>>(Ga, W3t, dis, b3, Hf, NN, HID);  // Hf row-major
    pool_part_kernel<<<NG * 4, 256, 0, stream>>>(Hf, goff, part);
    mlp_kernel<<<NG, 256, 0, stream>>>(part, goff, mol, rings, fcW1, fcb1, fcW2, fcb2, out);
}

// Round 10
// 333.704 us; speedup vs baseline: 1.6121x; 1.0529x over previous
//
#include <hip/hip_runtime.h>

#define NN 50000
#define NE 800000
#define NG 512
#define FIN 128
#define HID 256
#define NBUK 196   // buckets of 256 node ids: ceil(50000/256)
#define SEGSZ 2048 // segment size for the locality-preserving degree sort

typedef short short8 __attribute__((ext_vector_type(8)));
typedef float f32x4 __attribute__((ext_vector_type(4)));
typedef float f32x2 __attribute__((ext_vector_type(2)));
typedef unsigned short u16x8 __attribute__((ext_vector_type(8)));
typedef unsigned int u32x2 __attribute__((ext_vector_type(2)));
typedef unsigned int u32x4 __attribute__((ext_vector_type(4)));

static inline int cdiv(int a, int b) { return (a + b - 1) / b; }

static __device__ inline unsigned short f2bf(float f) {
    unsigned int u = __float_as_uint(f);
    unsigned int r = (u + 0x7FFF + ((u >> 16) & 1)) >> 16;  // RNE
    return (unsigned short)r;
}
static __device__ inline float bf2f(unsigned short h) {
    return __uint_as_float(((unsigned int)h) << 16);
}
static __device__ inline float bflo(unsigned int p) { return __uint_as_float(p << 16); }
static __device__ inline float bfhi(unsigned int p) { return __uint_as_float(p & 0xFFFF0000u); }

// packed fp32 add (gfx90a+): 1 instr for 2 lane-local f32 adds
static __device__ __forceinline__ f32x2 pkadd(f32x2 a, f32x2 b) {
    f32x2 r;
    asm("v_pk_add_f32 %0, %1, %2" : "=v"(r) : "v"(a), "v"(b));
    return r;
}

// ds_swizzle broadcast within each 16-lane group: all lanes get lane (group*16+J)'s value.
// BitMode offset: xor=0, or=J, and=0x10 (keep bit4 = group bit within each 32-lane half).
template <int J>
static __device__ __forceinline__ int bswz16(int v) {
    return __builtin_amdgcn_ds_swizzle(v, (J << 5) | 0x10);
}

typedef __attribute__((address_space(1))) unsigned int gu32;
typedef __attribute__((address_space(3))) unsigned int lu32;
static __device__ __forceinline__ void gload16(const unsigned short* g, unsigned short* l) {
    __builtin_amdgcn_global_load_lds((const gu32*)(const void*)g, (lu32*)(void*)l, 16, 0, 0);
}

// ---- CSR build, bucket-sort style (no per-edge global atomics) ----

// coarse 196-bucket histogram of dst, LDS-privatized
__global__ __launch_bounds__(256) void hist_bucket_kernel(const int* __restrict__ dst,
                                                          int* __restrict__ gbuk) {
    __shared__ int lh[NBUK];
    int tid = threadIdx.x;
    for (int j = tid; j < NBUK; j += 256) lh[j] = 0;
    __syncthreads();
    int base = blockIdx.x * 2048;
    #pragma unroll
    for (int k = 0; k < 8; ++k) {
        int i = base + k * 256 + tid;
        if (i < NE) atomicAdd(&lh[dst[i] >> 8], 1);
    }
    __syncthreads();
    for (int j = tid; j < NBUK; j += 256) if (lh[j]) atomicAdd(&gbuk[j], lh[j]);
}

// batch is sorted: goff by boundary detection, no atomics
__global__ void goff_kernel(const int* __restrict__ batch, int* __restrict__ goff) {
    int i = blockIdx.x * 256 + threadIdx.x;
    if (i >= NN) return;
    int b = batch[i];
    int pb = (i == 0) ? -1 : batch[i - 1];
    for (int g = pb + 1; g <= b; ++g) goff[g] = i;
    if (i == NN - 1) for (int g = b + 1; g <= NG; ++g) goff[g] = NN;
}

// single-block exclusive scan of gbuk[196] -> bukoff[197], plus cursor copy
__global__ void buk_scan_kernel(const int* __restrict__ gbuk, int* __restrict__ bukoff,
                                int* __restrict__ bukcur) {
    __shared__ int ws[4];
    int tid = threadIdx.x, lane = tid & 63, wid = tid >> 6;
    int v = (tid < NBUK) ? gbuk[tid] : 0;
    int incl = v;
    #pragma unroll
    for (int off = 1; off < 64; off <<= 1) {
        int u = __shfl_up(incl, off, 64);
        if (lane >= off) incl += u;
    }
    if (lane == 63) ws[wid] = incl;
    __syncthreads();
    int woff = 0;
    for (int w = 0; w < wid; ++w) woff += ws[w];
    int ex = woff + incl - v;
    if (tid < NBUK) { bukoff[tid] = ex; bukcur[tid] = ex; }
    if (tid == NBUK - 1) bukoff[NBUK] = ex + v;
}

// scatter edges into bucket-contiguous pairs[]; one global atomic per block per bucket
__global__ __launch_bounds__(256) void scatter_kernel(const int* __restrict__ src,
                                                      const int* __restrict__ dst,
                                                      int* __restrict__ bukcur,
                                                      unsigned int* __restrict__ pairs) {
    __shared__ int lh[NBUK];
    __shared__ int lbase[NBUK];
    int tid = threadIdx.x;
    for (int j = tid; j < NBUK; j += 256) lh[j] = 0;
    __syncthreads();
    int base = blockIdx.x * 2048;
    int d[8], s[8];
    #pragma unroll
    for (int k = 0; k < 8; ++k) {
        int i = base + k * 256 + tid;
        if (i < NE) {
            d[k] = dst[i]; s[k] = src[i];
            atomicAdd(&lh[d[k] >> 8], 1);
        } else d[k] = -1;
    }
    __syncthreads();
    for (int j = tid; j < NBUK; j += 256) lbase[j] = lh[j] ? atomicAdd(&bukcur[j], lh[j]) : 0;
    __syncthreads();
    for (int j = tid; j < NBUK; j += 256) lh[j] = 0;
    __syncthreads();
    #pragma unroll
    for (int k = 0; k < 8; ++k) {
        if (d[k] >= 0) {
            int b = d[k] >> 8;
            int loc = atomicAdd(&lh[b], 1);
            pairs[lbase[b] + loc] = ((unsigned int)s[k] << 16) | (unsigned int)(d[k] & 255);
        }
    }
}

// per-bucket fine CSR: row_ptr, col16 (pre-shifted src: col<<4 = u32x2 row offset for
// 64-feat slices), dis (one block per bucket)
__global__ __launch_bounds__(256) void local_csr_kernel(const unsigned int* __restrict__ pairs,
                                                        const int* __restrict__ bukoff,
                                                        int* __restrict__ row_ptr,
                                                        int* __restrict__ col16,
                                                        float* __restrict__ dis) {
    __shared__ int fcnt[256];
    __shared__ int foff[256];
    __shared__ int fws[4];
    int b = blockIdx.x, tid = threadIdx.x;
    int beg = bukoff[b], end = bukoff[b + 1];
    fcnt[tid] = 0;
    __syncthreads();
    for (int i = beg + tid; i < end; i += 256) atomicAdd(&fcnt[pairs[i] & 255], 1);
    __syncthreads();
    int lane = tid & 63, wid = tid >> 6;
    int v = fcnt[tid], incl = v;
    #pragma unroll
    for (int off = 1; off < 64; off <<= 1) {
        int u = __shfl_up(incl, off, 64);
        if (lane >= off) incl += u;
    }
    if (lane == 63) fws[wid] = incl;
    __syncthreads();
    int woff = 0;
    for (int w = 0; w < wid; ++w) woff += fws[w];
    int ex = woff + incl - v;  // exclusive fine offset
    foff[tid] = ex;
    int gid = b * 256 + tid;
    if (gid < NN) {
        row_ptr[gid] = beg + ex;
        dis[gid] = rsqrtf((float)v + 1.0f);
    }
    if (b == 0 && tid == 0) row_ptr[NN] = NE;
    __syncthreads();
    // scatter src into col16 using foff as LDS cursors
    for (int i = beg + tid; i < end; i += 256) {
        unsigned int p = pairs[i];
        int loc = atomicAdd(&foff[p & 255], 1);
        col16[beg + loc] = (int)(p >> 16) << 4;
    }
}

// SEGMENT-LOCAL degree sort -> work DESCRIPTORS. desc[idx] = {node, e_beg, e_end, dis}.
__global__ __launch_bounds__(256) void segperm_kernel(const int* __restrict__ row_ptr,
                                                      const float* __restrict__ dis,
                                                      u32x4* __restrict__ desc) {
    __shared__ int hist[256];
    __shared__ int ws[4];
    int tid = threadIdx.x;
    int base = blockIdx.x * SEGSZ;
    int segN = NN - base; if (segN > SEGSZ) segN = SEGSZ;
    hist[tid] = 0;
    __syncthreads();
    int dbin[8], rb[8], dreal[8];
    #pragma unroll
    for (int k = 0; k < 8; ++k) {
        int j = k * 256 + tid;
        if (j < segN) {
            rb[k] = row_ptr[base + j];
            dreal[k] = row_ptr[base + j + 1] - rb[k];
            int d = dreal[k] > 255 ? 255 : dreal[k];
            dbin[k] = d;
            atomicAdd(&hist[d], 1);
        } else dbin[k] = -1;
    }
    __syncthreads();
    int lane = tid & 63, wid = tid >> 6;
    int v = hist[tid], incl = v;
    #pragma unroll
    for (int off = 1; off < 64; off <<= 1) {
        int u = __shfl_up(incl, off, 64);
        if (lane >= off) incl += u;
    }
    if (lane == 63) ws[wid] = incl;
    __syncthreads();
    int woff = 0;
    for (int w = 0; w < wid; ++w) woff += ws[w];
    __syncthreads();
    hist[tid] = woff + incl - v;  // exclusive offset becomes bin cursor
    __syncthreads();
    #pragma unroll
    for (int k = 0; k < 8; ++k) {
        if (dbin[k] >= 0) {
            int rank = atomicAdd(&hist[dbin[k]], 1);
            int node = base + k * 256 + tid;
            u32x4 dd;
            dd.x = (unsigned int)node;
            dd.y = (unsigned int)rb[k];
            dd.z = (unsigned int)(rb[k] + dreal[k]);
            dd.w = __float_as_uint(dis[node]);
            desc[base + rank] = dd;
        }
    }
}

// Xb[s][i][f'] = bf16(dis[i] * x[i][f])  -- blocked layout, 2 slices of 64 feats
__global__ void cast_scale_kernel(const float* __restrict__ x, const float* __restrict__ dis,
                                  unsigned short* __restrict__ Xb, int n4) {
    int i = blockIdx.x * 256 + threadIdx.x;  // float4 index over [NN][128]
    if (i < n4) {
        int node = i >> 5;   // 32 float4 per row
        int f4 = i & 31;     // float4 index within row
        int s = f4 >> 4;     // slice = feat>>6
        int o = f4 & 15;     // float4 within the 64-feat slice
        float dv = dis[node];
        float4 v = ((const float4*)x)[i];
        ushort4 w;
        w.x = f2bf(dv * v.x); w.y = f2bf(dv * v.y); w.z = f2bf(dv * v.z); w.w = f2bf(dv * v.w);
        ((ushort4*)Xb)[((size_t)s * NN + (size_t)node) * 16 + o] = w;
    }
}

// all three weights transposed+cast in one dispatch: W [K,256] fp32 -> Wt [256,K] bf16
__global__ void tcast_all_kernel(const float* __restrict__ W1, const float* __restrict__ W2,
                                 const float* __restrict__ W3,
                                 unsigned short* __restrict__ W1t, unsigned short* __restrict__ W2t,
                                 unsigned short* __restrict__ W3t) {
    int idx = blockIdx.x * 256 + threadIdx.x;
    if (idx < FIN * 256) {
        int n = idx / FIN, k = idx - n * FIN;
        W1t[idx] = f2bf(W1[(size_t)k * 256 + n]);
    } else if (idx < FIN * 256 + HID * 256) {
        int t = idx - FIN * 256;
        int n = t / HID, k = t - n * HID;
        W2t[t] = f2bf(W2[(size_t)k * 256 + n]);
    } else {
        int t = idx - FIN * 256 - HID * 256;
        int n = t / HID, k = t - n * HID;
        W3t[t] = f2bf(W3[(size_t)k * 256 + n]);
    }
}

// 128x128 GEMM, BK=32, global_load_lds staging, LDS-bounce coalesced epilogue.
// A:[M,K] bf16 row-major, Bt:[256,K] bf16.
// MODE 0: Hs = bf16(dis[row]*relu(acc + bias[col])) -> BLOCKED [4][M][64] (feeds slice-agg)
// MODE 1: Hf = bf16(relu(acc + bias[col]))          -> row-major [M][256] (feeds pooling)
#define CLD 136   // C-tile LDS row stride in shorts (mult of 8 -> 16B-aligned rows)
template <int MODE>
__global__ __launch_bounds__(256) void gemm128_kernel(
        const unsigned short* __restrict__ A, const unsigned short* __restrict__ Bt,
        const float* __restrict__ dis, const float* __restrict__ bias,
        unsigned short* __restrict__ Cout, int M, int K) {
    __shared__ unsigned short smem[128 * CLD];  // K-loop: As=smem[0:4096], Bs=smem[4096:8192]
    unsigned short* As = smem;
    unsigned short* Bs = smem + 4096;
    const int tid = threadIdx.x;
    const int bm = blockIdx.x * 128, bn = blockIdx.y * 128;
    const int wave = tid >> 6, lane = tid & 63;
    const int l16 = lane & 15, quad = lane >> 4;
    const int wm = (wave & 1) * 64, wn = (wave >> 1) * 64;

    int srow0 = tid >> 2, skc = (tid & 3) * 8;
    int srow1 = (256 + tid) >> 2;
    int ar0 = bm + srow0; if (ar0 > M - 1) ar0 = M - 1;
    int ar1 = bm + srow1; if (ar1 > M - 1) ar1 = M - 1;

    f32x4 acc[4][4];
    #pragma unroll
    for (int i = 0; i < 4; ++i)
        #pragma unroll
        for (int j = 0; j < 4; ++j) acc[i][j] = (f32x4){0.f, 0.f, 0.f, 0.f};

    for (int k0 = 0; k0 < K; k0 += 32) {
        gload16(A + (size_t)ar0 * K + k0 + skc, &As[(size_t)tid * 8]);
        gload16(A + (size_t)ar1 * K + k0 + skc, &As[(size_t)(256 + tid) * 8]);
        gload16(Bt + (size_t)(bn + srow0) * K + k0 + skc, &Bs[(size_t)tid * 8]);
        gload16(Bt + (size_t)(bn + srow1) * K + k0 + skc, &Bs[(size_t)(256 + tid) * 8]);
        __syncthreads();
        short8 af[4], bf[4];
        #pragma unroll
        for (int mt = 0; mt < 4; ++mt) af[mt] = *(const short8*)&As[(wm + mt * 16 + l16) * 32 + quad * 8];
        #pragma unroll
        for (int nt = 0; nt < 4; ++nt) bf[nt] = *(const short8*)&Bs[(wn + nt * 16 + l16) * 32 + quad * 8];
        #pragma unroll
        for (int mt = 0; mt < 4; ++mt)
            #pragma unroll
            for (int nt = 0; nt < 4; ++nt)
                acc[mt][nt] = __builtin_amdgcn_mfma_f32_16x16x32_bf16(af[mt], bf[nt], acc[mt][nt], 0, 0, 0);
        __syncthreads();
    }
    // phase 1: acc -> LDS tile (bf16), bias/relu/dis applied.  C/D: col=l16+16nt+wn, row=quad*4+r+16mt+wm
    float bv[4];
    #pragma unroll
    for (int nt = 0; nt < 4; ++nt) bv[nt] = bias[bn + wn + nt * 16 + l16];
    #pragma unroll
    for (int mt = 0; mt < 4; ++mt) {
        #pragma unroll
        for (int r = 0; r < 4; ++r) {
            int lrow = wm + mt * 16 + quad * 4 + r;
            int grow = bm + lrow; if (grow > M - 1) grow = M - 1;
            float dv = (MODE == 0) ? dis[grow] : 1.0f;
            #pragma unroll
            for (int nt = 0; nt < 4; ++nt) {
                float v = fmaxf(acc[mt][nt][r] + bv[nt], 0.f);
                if (MODE == 0) v *= dv;
                smem[lrow * CLD + wn + nt * 16 + l16] = f2bf(v);
            }
        }
    }
    __syncthreads();
    // phase 2: LDS -> global, 16B coalesced chunks (2048 chunks, 8 per thread)
    for (int c = tid; c < 2048; c += 256) {
        int lrow = c >> 4, coff = (c & 15) << 3;
        int grow = bm + lrow;
        if (grow < M) {
            if (MODE == 0) {
                int gcol = bn + coff;
                int s = gcol >> 6, o = gcol & 63;  // blocked [4][M][64]
                *(u16x8*)(Cout + ((size_t)s * M + (size_t)grow) * 64 + o) =
                    *(const u16x8*)&smem[lrow * CLD + coff];
            } else {
                *(u16x8*)(Cout + (size_t)grow * HID + bn + coff) =
                    *(const u16x8*)&smem[lrow * CLD + coff];
            }
        }
    }
}
#undef CLD

// Feature-slice aggregation v5: 64-FEAT slices, 128 B gathers (16 lanes x 8 B/node).
// Request-count halving vs v4: round-9 PMC showed agg256 at ~93% of the L2
// request-service ceiling (6.4 M x 64 B requests vs 34.5 TB/s L2); only bytes/request
// is a free variable. Slice table = 6.4 MB (> 4 MB L2): ~60% L2-hit, misses served
// by the 256 MB L3 (tables resident; FETCH stays compulsory).
// S slices of 64 feats (S=2 for FIN, S=4 for HID); slice = bid&(S-1) XCD pinning;
// 16 nodes/block; 16-deep batches + 15-wide predicated tail; LPT chunk reversal.
template <int S>
__global__ __launch_bounds__(256) void agg_slice_kernel(
        const unsigned short* __restrict__ Hb, const u32x4* __restrict__ desc,
        const int* __restrict__ col16,
        unsigned short* __restrict__ Out, int n, int nchunk) {
    constexpr int LOGS = (S == 4) ? 2 : 1;
    int bid = blockIdx.x;
    int s = bid & (S - 1);
    int chunk = nchunk - 1 - (bid >> LOGS);  // reversed: high-degree chunks first
    int idx = chunk * 16 + (threadIdx.x >> 4);
    if (idx >= n) return;
    int lane16 = threadIdx.x & 15;
    u32x4 d = desc[idx];
    int node = (int)d.x;
    int e = (int)d.y, eend = (int)d.z;
    float dv = __uint_as_float(d.w);
    const u32x2* Hv = (const u32x2*)Hb + (size_t)s * NN * 16;
    u32x2 p = Hv[node * 16 + lane16];  // self loop (128 B per 16-lane group)
    f32x2 a01 = {bflo(p.x), bfhi(p.x)};
    f32x2 a23 = {bflo(p.y), bfhi(p.y)};

    // 16-deep batches: 1 col vector (16 consecutive ints), 16 gathers in flight
    for (; e + 16 <= eend; e += 16) {
        int cv = col16[e + lane16];
        u32x2 m[16];
#define G0(J) m[J] = Hv[bswz16<J>(cv) + lane16];
        G0(0) G0(1) G0(2) G0(3) G0(4) G0(5) G0(6) G0(7)
        G0(8) G0(9) G0(10) G0(11) G0(12) G0(13) G0(14) G0(15)
#undef G0
        #pragma unroll
        for (int j = 0; j < 16; ++j) {
            f32x2 lo = {bflo(m[j].x), bfhi(m[j].x)};
            f32x2 hi = {bflo(m[j].y), bfhi(m[j].y)};
            a01 = pkadd(a01, lo);
            a23 = pkadd(a23, hi);
        }
    }
    // masked tail (1..15 edges): batched predicated gathers, no serial chain
    int t = eend - e;
    if (t > 0) {
        int il = e + lane16; if (il >= eend) il = eend - 1;  // clamp lanes >= t
        int cv = col16[il];
        u32x2 m[15];
#define GT(J) if (J < t) m[J] = Hv[bswz16<J>(cv) + lane16];
        GT(0) GT(1) GT(2) GT(3) GT(4) GT(5) GT(6) GT(7)
        GT(8) GT(9) GT(10) GT(11) GT(12) GT(13) GT(14)
#undef GT
#define AT(J) if (J < t) { f32x2 lo = {bflo(m[J].x), bfhi(m[J].x)}; \
                           f32x2 hi = {bflo(m[J].y), bfhi(m[J].y)}; \
                           a01 = pkadd(a01, lo); a23 = pkadd(a23, hi); }
        AT(0) AT(1) AT(2) AT(3) AT(4) AT(5) AT(6) AT(7)
        AT(8) AT(9) AT(10) AT(11) AT(12) AT(13) AT(14)
#undef AT
    }
    u32x2 o;
    o.x = (unsigned int)f2bf(dv * a01.x) | ((unsigned int)f2bf(dv * a01.y) << 16);
    o.y = (unsigned int)f2bf(dv * a23.x) | ((unsigned int)f2bf(dv * a23.y) << 16);
    __builtin_nontemporal_store(o, (u32x2*)Out + (size_t)node * (S * 16) + s * 16 + lane16);
}

// Pooling stage 1: 4 blocks per graph, threads [node_par=4][feat=64 x f32x4].
__global__ __launch_bounds__(256) void pool_part_kernel(
        const unsigned short* __restrict__ H, const int* __restrict__ goff,
        float* __restrict__ part) {
    __shared__ float red[3][64][4];
    int bid = blockIdx.x;
    int g = bid >> 2, q = bid & 3;
    int beg = goff[g], end = goff[g + 1];
    int len = end - beg;
    int qb = beg + ((len * q) >> 2), qe = beg + ((len * (q + 1)) >> 2);
    int tp = threadIdx.x >> 6, tf = threadIdx.x & 63;
    float4 acc = make_float4(0.f, 0.f, 0.f, 0.f);
    int i = qb + tp;
    for (; i + 12 < qe; i += 16) {  // 4 rows/thread in flight (stride 4 = node_par)
        ushort4 v0 = *(const ushort4*)&H[(size_t)(i     ) * HID + tf * 4];
        ushort4 v1 = *(const ushort4*)&H[(size_t)(i +  4) * HID + tf * 4];
        ushort4 v2 = *(const ushort4*)&H[(size_t)(i +  8) * HID + tf * 4];
        ushort4 v3 = *(const ushort4*)&H[(size_t)(i + 12) * HID + tf * 4];
        acc.x += bf2f(v0.x) + bf2f(v1.x) + bf2f(v2.x) + bf2f(v3.x);
        acc.y += bf2f(v0.y) + bf2f(v1.y) + bf2f(v2.y) + bf2f(v3.y);
        acc.z += bf2f(v0.z) + bf2f(v1.z) + bf2f(v2.z) + bf2f(v3.z);
        acc.w += bf2f(v0.w) + bf2f(v1.w) + bf2f(v2.w) + bf2f(v3.w);
    }
    for (; i < qe; i += 4) {
        ushort4 v = *(const ushort4*)&H[(size_t)i * HID + tf * 4];
        acc.x += bf2f(v.x); acc.y += bf2f(v.y); acc.z += bf2f(v.z); acc.w += bf2f(v.w);
    }
    if (tp > 0) {
        red[tp - 1][tf][0] = acc.x; red[tp - 1][tf][1] = acc.y;
        red[tp - 1][tf][2] = acc.z; red[tp - 1][tf][3] = acc.w;
    }
    __syncthreads();
    if (tp == 0) {
        acc.x += red[0][tf][0] + red[1][tf][0] + red[2][tf][0];
        acc.y += red[0][tf][1] + red[1][tf][1] + red[2][tf][1];
        acc.z += red[0][tf][2] + red[1][tf][2] + red[2][tf][2];
        acc.w += red[0][tf][3] + red[1][tf][3] + red[2][tf][3];
        ((float4*)part)[(size_t)bid * 64 + tf] = acc;
    }
}

// Pooling stage 2 + MLP: sum 4 partials, mean, concat, FC1 (8-way batched loads),
// FC2 as 16x16 partial dots + LDS reduce.
__global__ __launch_bounds__(256) void mlp_kernel(
        const float* __restrict__ part, const int* __restrict__ goff,
        const float* __restrict__ mol, const float* __restrict__ rings,
        const float* __restrict__ fcW1, const float* __restrict__ fcb1,
        const float* __restrict__ fcW2, const float* __restrict__ fcb2,
        float* __restrict__ out) {
    __shared__ float s_hg[258];
    __shared__ float s_t[196];
    __shared__ float s_p[16][16];
    int g = blockIdx.x, tid = threadIdx.x;
    int len = goff[g + 1] - goff[g];
    const float* pg = part + (size_t)g * 1024;
    float v = pg[tid] + pg[256 + tid] + pg[512 + tid] + pg[768 + tid];
    s_hg[tid] = v / fmaxf((float)len, 1.0f);
    if (tid == 0) { s_hg[256] = mol[g]; s_hg[257] = rings[g]; }
    __syncthreads();
    if (tid < 196) {
        float a = fcb1[tid];
        int k = 0;
        for (; k + 8 <= 258; k += 8) {  // 8 weight loads in flight
            float w0 = fcW1[(k + 0) * 196 + tid];
            float w1 = fcW1[(k + 1) * 196 + tid];
            float w2 = fcW1[(k + 2) * 196 + tid];
            float w3 = fcW1[(k + 3) * 196 + tid];
            float w4 = fcW1[(k + 4) * 196 + tid];
            float w5 = fcW1[(k + 5) * 196 + tid];
            float w6 = fcW1[(k + 6) * 196 + tid];
            float w7 = fcW1[(k + 7) * 196 + tid];
            a = fmaf(s_hg[k + 0], w0, a); a = fmaf(s_hg[k + 1], w1, a);
            a = fmaf(s_hg[k + 2], w2, a); a = fmaf(s_hg[k + 3], w3, a);
            a = fmaf(s_hg[k + 4], w4, a); a = fmaf(s_hg[k + 5], w5, a);
            a = fmaf(s_hg[k + 6], w6, a); a = fmaf(s_hg[k + 7], w7, a);
        }
        for (; k < 258; ++k) a = fmaf(s_hg[k], fcW1[k * 196 + tid], a);
        s_t[tid] = fmaxf(a, 0.f);
    }
    __syncthreads();
    {
        int o = tid & 15, kp = tid >> 4;
        float a = 0.f;
        for (int k = kp; k < 196; k += 16) a = fmaf(s_t[k], fcW2[k * 16 + o], a);
        s_p[kp][o] = a;
    }
    __syncthreads();
    if (tid < 16) {
        float a = fcb2[tid];
        #pragma unroll
        for (int kp = 0; kp < 16; ++kp) a += s_p[kp][tid];
        out[g * 16 + tid] = a;
    }
}

extern "C" void kernel_launch(void* const* d_in, const int* in_sizes, int n_in,
                              void* d_out, int out_size, void* d_ws, size_t ws_size,
                              hipStream_t stream) {
    const float* x     = (const float*)d_in[0];
    const int*   ei    = (const int*)d_in[1];
    const int*   batch = (const int*)d_in[2];
    const float* mol   = (const float*)d_in[3];
    const float* rings = (const float*)d_in[4];
    const float* W1 = (const float*)d_in[5];
    const float* b1 = (const float*)d_in[6];
    const float* W2 = (const float*)d_in[7];
    const float* b2 = (const float*)d_in[8];
    const float* W3 = (const float*)d_in[9];
    const float* b3 = (const float*)d_in[10];
    const float* fcW1 = (const float*)d_in[11];
    const float* fcb1 = (const float*)d_in[12];
    const float* fcW2 = (const float*)d_in[13];
    const float* fcb2 = (const float*)d_in[14];
    float* out = (float*)d_out;
    const int* src = ei;
    const int* dst = ei + NE;

    char* w = (char*)d_ws;
    auto alloc = [&](size_t bytes) {
        char* p = w;
        w += (bytes + 255) & ~(size_t)255;
        return p;
    };
    int*   gbuk    = (int*)alloc((size_t)NBUK * 4);
    int*   bukoff  = (int*)alloc((size_t)(NBUK + 1) * 4);
    int*   bukcur  = (int*)alloc((size_t)NBUK * 4);
    int*   row_ptr = (int*)alloc((size_t)(NN + 1) * 4);
    int*   goff    = (int*)alloc((size_t)(NG + 1) * 4);
    float* dis     = (float*)alloc((size_t)NN * 4);
    u32x4* desc    = (u32x4*)alloc((size_t)NN * 16);
    unsigned int* pairs = (unsigned int*)alloc((size_t)NE * 4);
    int*   col16   = (int*)alloc((size_t)NE * 4);
    float* part    = (float*)alloc((size_t)NG * 4 * 256 * 4);  // [2048][256] fp32 pool partials
    unsigned short* Xs  = (unsigned short*)alloc((size_t)NN * FIN * 2);  // blocked [2][NN][64]
    unsigned short* Xa  = (unsigned short*)alloc((size_t)NN * FIN * 2);  // row-major
    unsigned short* Hs  = (unsigned short*)alloc((size_t)NN * HID * 2);  // blocked [4][NN][64]
    unsigned short* Ga  = (unsigned short*)alloc((size_t)NN * HID * 2);  // row-major
    unsigned short* Hf  = (unsigned short*)alloc((size_t)NN * HID * 2);  // row-major
    unsigned short* W1t = (unsigned short*)alloc((size_t)FIN * HID * 2);
    unsigned short* W2t = (unsigned short*)alloc((size_t)HID * HID * 2);
    unsigned short* W3t = (unsigned short*)alloc((size_t)HID * HID * 2);

    hipMemsetAsync(gbuk, 0, (size_t)NBUK * 4, stream);
    int eb = cdiv(NE, 2048);  // 391
    hist_bucket_kernel<<<eb, 256, 0, stream>>>(dst, gbuk);
    goff_kernel<<<cdiv(NN, 256), 256, 0, stream>>>(batch, goff);
    buk_scan_kernel<<<1, 256, 0, stream>>>(gbuk, bukoff, bukcur);
    scatter_kernel<<<eb, 256, 0, stream>>>(src, dst, bukcur, pairs);
    local_csr_kernel<<<NBUK, 256, 0, stream>>>(pairs, bukoff, row_ptr, col16, dis);
    segperm_kernel<<<cdiv(NN, SEGSZ), 256, 0, stream>>>(row_ptr, dis, desc);

    cast_scale_kernel<<<cdiv(NN * FIN / 4, 256), 256, 0, stream>>>(x, dis, Xs, NN * FIN / 4);
    tcast_all_kernel<<<cdiv((FIN + HID + HID) * 256, 256), 256, 0, stream>>>(W1, W2, W3, W1t, W2t, W3t);

    dim3 ggrid(cdiv(NN, 128), 2);
    int achunks = cdiv(NN, 16);  // 3125 (16 nodes per block)
    // all layers: aggregate-then-transform (aggregation commutes with @W)
    agg_slice_kernel<2><<<2 * achunks, 256, 0, stream>>>(Xs, desc, col16, Xa, NN, achunks);
    gemm128_kernel<0><<<ggrid, 256, 0, stream>>>(Xa, W1t, dis, b1, Hs, NN, FIN);  // Hs1 blocked
    agg_slice_kernel<4><<<4 * achunks, 256, 0, stream>>>(Hs, desc, col16, Ga, NN, achunks);
    gemm128_kernel<0><<<ggrid, 256, 0, stream>>>(Ga, W2t, dis, b2, Hs, NN, HID);  // Hs2 blocked
    agg_slice_kernel<4><<<4 * achunks, 256, 0, stream>>>(Hs, desc, col16, Ga, NN, achunks);
    gemm128_kernel<1><<<ggrid, 256, 0, stream>>>(Ga, W3t, dis, b3, Hf, NN, HID);  // Hf row-major
    pool_part_kernel<<<NG * 4, 256, 0, stream>>>(Hf, goff, part);
    mlp_kernel<<<NG, 256, 0, stream>>>(part, goff, mol, rings, fcW1, fcb1, fcW2, fcb2, out);
}